// Round 2
// baseline (847.903 us; speedup 1.0000x reference)
//
#include <hip/hip_runtime.h>

#define DIM 128
#define NT 32   // nodes per block for GEMM kernels

// ---------------- KV projection: K = x@Wk^T+bk, V = x@Wv^T+bv ----------------
// Register-tiled: thread = 4 nodes x 8 outs (f = fg+32k, k<4 -> K, k>=4 -> V)
__global__ __launch_bounds__(256) void kv_proj(const float* __restrict__ x,
    const float* __restrict__ Wk, const float* __restrict__ bk,
    const float* __restrict__ Wv, const float* __restrict__ bv,
    float* __restrict__ K, float* __restrict__ V, int N) {
  __shared__ float xs[NT * DIM];
  int base = blockIdx.x * NT;
  int tid = threadIdx.x;
  // stage x tile (float4, coalesced)
  for (int i = tid; i < NT * (DIM / 4); i += 256) {
    int nn = i >> 5;
    float4 v = (base + nn < N) ? ((const float4*)x)[(size_t)base * (DIM / 4) + i]
                               : make_float4(0.f, 0.f, 0.f, 0.f);
    ((float4*)xs)[i] = v;
  }
  __syncthreads();
  int fg = tid & 31, mg = tid >> 5;
  int m0 = mg * 4;
  const float* wr[8];
#pragma unroll
  for (int k = 0; k < 8; k++) {
    int f = fg + 32 * k;
    wr[k] = (k < 4) ? (Wk + (size_t)f * DIM) : (Wv + (size_t)(f - 128) * DIM);
  }
  float acc[8][4];
#pragma unroll
  for (int k = 0; k < 8; k++)
#pragma unroll
    for (int m = 0; m < 4; m++) acc[k][m] = 0.f;
  for (int j = 0; j < DIM; j += 4) {
    float4 xv[4];
#pragma unroll
    for (int m = 0; m < 4; m++) xv[m] = *(const float4*)&xs[(m0 + m) * DIM + j];
#pragma unroll
    for (int k = 0; k < 8; k++) {
      float4 w = *(const float4*)&wr[k][j];
#pragma unroll
      for (int m = 0; m < 4; m++)
        acc[k][m] += w.x * xv[m].x + w.y * xv[m].y + w.z * xv[m].z + w.w * xv[m].w;
    }
  }
#pragma unroll
  for (int k = 0; k < 8; k++) {
    int f = fg + 32 * k;
    float b = (k < 4) ? bk[f] : bv[f - 128];
    float* O = (k < 4) ? K : V;
    int fo = (k < 4) ? f : f - 128;
#pragma unroll
    for (int m = 0; m < 4; m++) {
      int n = base + m0 + m;
      if (n < N) O[(size_t)n * DIM + fo] = acc[k][m] + b;
    }
  }
}

// ---------------- CSR build ----------------
__global__ __launch_bounds__(256) void hist_kernel(const int* __restrict__ ei,
                                                   int* __restrict__ cnt, int E) {
  int e = blockIdx.x * 256 + threadIdx.x;
  if (e < E) atomicAdd(&cnt[ei[E + e]], 1);  // dst = ei[E..2E)
}

__global__ __launch_bounds__(256) void scanA(const int* __restrict__ cnt,
    int* __restrict__ rs, int* __restrict__ bsum, int N) {
  __shared__ int s[256];
  int t = threadIdx.x;
  int i = blockIdx.x * 256 + t;
  int v = (i < N) ? cnt[i] : 0;
  s[t] = v;
  __syncthreads();
  for (int off = 1; off < 256; off <<= 1) {
    int add = (t >= off) ? s[t - off] : 0;
    __syncthreads();
    s[t] += add;
    __syncthreads();
  }
  if (i < N) rs[i] = s[t] - v;  // exclusive
  if (t == 255) bsum[blockIdx.x] = s[t];
}

__global__ __launch_bounds__(256) void scanB(int* __restrict__ bsum, int nb) {
  __shared__ int s[256];
  int t = threadIdx.x;
  int v = (t < nb) ? bsum[t] : 0;
  s[t] = v;
  __syncthreads();
  for (int off = 1; off < 256; off <<= 1) {
    int add = (t >= off) ? s[t - off] : 0;
    __syncthreads();
    s[t] += add;
    __syncthreads();
  }
  if (t < nb) bsum[t] = s[t] - v;  // exclusive
}

__global__ __launch_bounds__(256) void scanC(int* __restrict__ rs,
    const int* __restrict__ bsum, int* __restrict__ cursor, int N, int E) {
  int i = blockIdx.x * 256 + threadIdx.x;
  if (i < N) {
    int v = rs[i] + bsum[blockIdx.x];
    rs[i] = v;
    cursor[i] = v;
  }
  if (i == 0) rs[N] = E;
}

__global__ __launch_bounds__(256) void scatter_kernel(const int* __restrict__ ei,
    int* __restrict__ cursor, int* __restrict__ esrc, int E) {
  int e = blockIdx.x * 256 + threadIdx.x;
  if (e < E) {
    int d = ei[E + e];
    int pos = atomicAdd(&cursor[d], 1);
    esrc[pos] = ei[e];  // store src node id
  }
}

// ---------------- fused attention aggregate: one wave per dst node ----------
__global__ __launch_bounds__(256) void attn_agg(const float* __restrict__ K,
    const float* __restrict__ V, const float* __restrict__ x,
    const int* __restrict__ rs, const int* __restrict__ esrc,
    float* __restrict__ attn, int N) {
  int wave = threadIdx.x >> 6, lane = threadIdx.x & 63;
  int n = blockIdx.x * 4 + wave;
  if (n >= N) return;
  float2 xv = *(const float2*)&x[n * DIM + 2 * lane];
  int beg = rs[n], end = rs[n + 1];
  float accx = 0.f, accy = 0.f, dloc = 0.f;
  for (int e = beg; e < end; e++) {
    int src = esrc[e];
    float2 kv = *(const float2*)&K[src * DIM + 2 * lane];
    float p = kv.x * xv.x + kv.y * xv.y;
    p += __shfl_xor(p, 1);
    p += __shfl_xor(p, 2);
    p += __shfl_xor(p, 4);
    float ev = expf(p * 0.25f);
    dloc += ev;
    float2 vv = *(const float2*)&V[src * DIM + 2 * lane];
    accx += vv.x * ev;
    accy += vv.y * ev;
  }
  float inv = 1.0f / (dloc + 1e-16f);
  *(float2*)&attn[n * DIM + 2 * lane] = make_float2(accx * inv, accy * inv);
}

// ---------------- O-projection + residual + BN1 stats ----------------
// thread = 4 nodes x 4 outs (f = fg+32k)
__global__ __launch_bounds__(256) void o_proj_bn(const float* __restrict__ attn,
    const float* __restrict__ x, const float* __restrict__ Wo,
    const float* __restrict__ bo, float* __restrict__ t,
    float* __restrict__ stats, int N) {
  __shared__ float as_[NT * DIM];
  __shared__ float redS[8 * 128];
  __shared__ float redQ[8 * 128];
  int base = blockIdx.x * NT;
  int tid = threadIdx.x;
  for (int i = tid; i < NT * (DIM / 4); i += 256) {
    int nn = i >> 5;
    float4 v = (base + nn < N) ? ((const float4*)attn)[(size_t)base * (DIM / 4) + i]
                               : make_float4(0.f, 0.f, 0.f, 0.f);
    ((float4*)as_)[i] = v;
  }
  __syncthreads();
  int fg = tid & 31, mg = tid >> 5;
  int m0 = mg * 4;
  float acc[4][4];
#pragma unroll
  for (int k = 0; k < 4; k++)
#pragma unroll
    for (int m = 0; m < 4; m++) acc[k][m] = 0.f;
  for (int j = 0; j < DIM; j += 4) {
    float4 xv[4];
#pragma unroll
    for (int m = 0; m < 4; m++) xv[m] = *(const float4*)&as_[(m0 + m) * DIM + j];
#pragma unroll
    for (int k = 0; k < 4; k++) {
      float4 w = *(const float4*)&Wo[(size_t)(fg + 32 * k) * DIM + j];
#pragma unroll
      for (int m = 0; m < 4; m++)
        acc[k][m] += w.x * xv[m].x + w.y * xv[m].y + w.z * xv[m].z + w.w * xv[m].w;
    }
  }
#pragma unroll
  for (int k = 0; k < 4; k++) {
    int f = fg + 32 * k;
    float b = bo[f];
    float s = 0.f, sq = 0.f;
#pragma unroll
    for (int m = 0; m < 4; m++) {
      int n = base + m0 + m;
      if (n < N) {
        float tv = acc[k][m] + b + x[(size_t)n * DIM + f];
        t[(size_t)n * DIM + f] = tv;
        s += tv;
        sq += tv * tv;
      }
    }
    redS[mg * 128 + f] = s;
    redQ[mg * 128 + f] = sq;
  }
  __syncthreads();
  if (tid < 128) {
    float s = 0.f, sq = 0.f;
#pragma unroll
    for (int g = 0; g < 8; g++) {
      s += redS[g * 128 + tid];
      sq += redQ[g * 128 + tid];
    }
    atomicAdd(&stats[tid], s);
    atomicAdd(&stats[128 + tid], sq);
  }
}

// ---------------- BN finalize: y = t*a + c ----------------
__global__ void bn_fin(const float* __restrict__ stats, const float* __restrict__ g,
                       const float* __restrict__ b, float* __restrict__ coef,
                       float invN) {
  int f = threadIdx.x;  // 128 threads
  float mu = stats[f] * invN;
  float var = stats[128 + f] * invN - mu * mu;
  float a = rsqrtf(var + 1e-5f) * g[f];
  coef[f] = a;
  coef[128 + f] = b[f] - mu * a;
}

// ---------------- FFN (+BN1 apply on input, BN2 stats on output) -------------
__global__ __launch_bounds__(256) void ffn_bn(const float* __restrict__ t,
    const float* __restrict__ coef1, const float* __restrict__ W1,
    const float* __restrict__ b1, const float* __restrict__ W2,
    const float* __restrict__ b2, float* __restrict__ z,
    float* __restrict__ stats2, int N) {
  __shared__ float hs[NT * DIM];    // 16 KB
  __shared__ float us[NT * 256];    // 32 KB; reused as red after stage B j-loop
  int base = blockIdx.x * NT;
  int tid = threadIdx.x;
  int fg = tid & 31, mg = tid >> 5;
  int m0 = mg * 4;
  // stage h tile with BN1 applied
  for (int i = tid; i < NT * DIM; i += 256) {
    int nn = i >> 7, f = i & 127;
    hs[i] = (base + nn < N) ? t[(size_t)base * DIM + i] * coef1[f] + coef1[128 + f] : 0.f;
  }
  __syncthreads();
  {  // stage A: u = relu(h@W1^T + b1), 256 outs, thread = 4m x 8f
    float acc[8][4];
#pragma unroll
    for (int k = 0; k < 8; k++)
#pragma unroll
      for (int m = 0; m < 4; m++) acc[k][m] = 0.f;
    for (int j = 0; j < DIM; j += 4) {
      float4 xv[4];
#pragma unroll
      for (int m = 0; m < 4; m++) xv[m] = *(const float4*)&hs[(m0 + m) * DIM + j];
#pragma unroll
      for (int k = 0; k < 8; k++) {
        float4 w = *(const float4*)&W1[(size_t)(fg + 32 * k) * DIM + j];
#pragma unroll
        for (int m = 0; m < 4; m++)
          acc[k][m] += w.x * xv[m].x + w.y * xv[m].y + w.z * xv[m].z + w.w * xv[m].w;
      }
    }
#pragma unroll
    for (int k = 0; k < 8; k++) {
      int f = fg + 32 * k;
      float b = b1[f];
#pragma unroll
      for (int m = 0; m < 4; m++) us[(m0 + m) * 256 + f] = fmaxf(acc[k][m] + b, 0.f);
    }
  }
  __syncthreads();
  // stage B: z = h + u@W2^T + b2, thread = 4m x 4f
  float acc2[4][4];
#pragma unroll
  for (int k = 0; k < 4; k++)
#pragma unroll
    for (int m = 0; m < 4; m++) acc2[k][m] = 0.f;
  for (int j = 0; j < 256; j += 4) {
    float4 xv[4];
#pragma unroll
    for (int m = 0; m < 4; m++) xv[m] = *(const float4*)&us[(m0 + m) * 256 + j];
#pragma unroll
    for (int k = 0; k < 4; k++) {
      float4 w = *(const float4*)&W2[(size_t)(fg + 32 * k) * 256 + j];
#pragma unroll
      for (int m = 0; m < 4; m++)
        acc2[k][m] += w.x * xv[m].x + w.y * xv[m].y + w.z * xv[m].z + w.w * xv[m].w;
    }
  }
  __syncthreads();  // us j-loop done; reuse us as reduction buffer
  float* redS = us;
  float* redQ = us + 8 * 128;
#pragma unroll
  for (int k = 0; k < 4; k++) {
    int f = fg + 32 * k;
    float b = b2[f];
    float s = 0.f, sq = 0.f;
#pragma unroll
    for (int m = 0; m < 4; m++) {
      int n = base + m0 + m;
      if (n < N) {
        float zv = hs[(m0 + m) * DIM + f] + acc2[k][m] + b;
        z[(size_t)n * DIM + f] = zv;
        s += zv;
        sq += zv * zv;
      }
    }
    redS[mg * 128 + f] = s;
    redQ[mg * 128 + f] = sq;
  }
  __syncthreads();
  if (tid < 128) {
    float s = 0.f, sq = 0.f;
#pragma unroll
    for (int g = 0; g < 8; g++) {
      s += redS[g * 128 + tid];
      sq += redQ[g * 128 + tid];
    }
    atomicAdd(&stats2[tid], s);
    atomicAdd(&stats2[128 + tid], sq);
  }
}

// ---------------- final BN2 apply ----------------
__global__ __launch_bounds__(256) void final_apply(const float* __restrict__ z,
    const float* __restrict__ coef2, float* __restrict__ out, int total4) {
  int i = blockIdx.x * 256 + threadIdx.x;
  if (i >= total4) return;
  int f = (i * 4) & 127;
  float4 zv = ((const float4*)z)[i];
  float4 o;
  o.x = zv.x * coef2[f] + coef2[128 + f];
  o.y = zv.y * coef2[f + 1] + coef2[128 + f + 1];
  o.z = zv.z * coef2[f + 2] + coef2[128 + f + 2];
  o.w = zv.w * coef2[f + 3] + coef2[128 + f + 3];
  ((float4*)out)[i] = o;
}

extern "C" void kernel_launch(void* const* d_in, const int* in_sizes, int n_in,
                              void* d_out, int out_size, void* d_ws, size_t ws_size,
                              hipStream_t stream) {
  const float* x = (const float*)d_in[0];
  const int* ei = (const int*)d_in[1];
  const float* Wk = (const float*)d_in[2];
  const float* bk = (const float*)d_in[3];
  const float* Wv = (const float*)d_in[4];
  const float* bv = (const float*)d_in[5];
  const float* Wo = (const float*)d_in[6];
  const float* bo = (const float*)d_in[7];
  const float* bn1_g = (const float*)d_in[8];
  const float* bn1_b = (const float*)d_in[9];
  const float* W1 = (const float*)d_in[10];
  const float* b1 = (const float*)d_in[11];
  const float* W2 = (const float*)d_in[12];
  const float* b2 = (const float*)d_in[13];
  const float* bn2_g = (const float*)d_in[14];
  const float* bn2_b = (const float*)d_in[15];
  float* out = (float*)d_out;

  int N = in_sizes[0] / DIM;   // 40000
  int E = in_sizes[1] / 2;     // 640000

  float* Kbuf = (float*)d_ws;
  float* Vbuf = Kbuf + (size_t)N * DIM;
  float* attn = Vbuf + (size_t)N * DIM;
  float* tbuf = Kbuf;
  float* zbuf = Vbuf;
  float* stats = attn + (size_t)N * DIM;  // 512 floats: stats1 | stats2
  float* coef = stats + 512;              // 512 floats
  int* cnt = (int*)(coef + 512);
  int* rs = cnt + N;
  int* cursor = rs + N + 1;
  int* esrc = cursor + N;
  int* bsum = esrc + E;

  int nblk = (N + 255) / 256;

  hipMemsetAsync(cnt, 0, (size_t)N * sizeof(int), stream);
  hipMemsetAsync(stats, 0, 512 * sizeof(float), stream);

  kv_proj<<<(N + NT - 1) / NT, 256, 0, stream>>>(x, Wk, bk, Wv, bv, Kbuf, Vbuf, N);
  hist_kernel<<<(E + 255) / 256, 256, 0, stream>>>(ei, cnt, E);
  scanA<<<nblk, 256, 0, stream>>>(cnt, rs, bsum, N);
  scanB<<<1, 256, 0, stream>>>(bsum, nblk);
  scanC<<<nblk, 256, 0, stream>>>(rs, bsum, cursor, N, E);
  scatter_kernel<<<(E + 255) / 256, 256, 0, stream>>>(ei, cursor, esrc, E);
  attn_agg<<<(N + 3) / 4, 256, 0, stream>>>(Kbuf, Vbuf, x, rs, esrc, attn, N);
  o_proj_bn<<<(N + NT - 1) / NT, 256, 0, stream>>>(attn, x, Wo, bo, tbuf, stats, N);
  bn_fin<<<1, 128, 0, stream>>>(stats, bn1_g, bn1_b, coef, 1.0f / N);
  ffn_bn<<<(N + NT - 1) / NT, 256, 0, stream>>>(tbuf, coef, W1, b1, W2, b2, zbuf,
                                                stats + 256, N);
  bn_fin<<<1, 128, 0, stream>>>(stats + 256, bn2_g, bn2_b, coef + 256, 1.0f / N);
  final_apply<<<((N * DIM / 4) + 255) / 256, 256, 0, stream>>>(zbuf, coef + 256, out,
                                                               N * DIM / 4);
}

// Round 3
// 531.650 us; speedup vs baseline: 1.5949x; 1.5949x over previous
//
#include <hip/hip_runtime.h>

#define DIM 128
#define NT 32   // nodes per block for GEMM kernels

typedef __attribute__((ext_vector_type(4))) _Float16 half4;

__device__ __forceinline__ float dot4(float4 a, float4 b) {
  return a.x * b.x + a.y * b.y + a.z * b.z + a.w * b.w;
}

// ---------------- KV projection: K = x@Wk^T+bk, V = x@Wv^T+bv ----------------
// Weights staged to LDS in 32-col j-panels, row stride 36 (conflict-free b128).
__global__ __launch_bounds__(256) void kv_proj(const float* __restrict__ x,
    const float* __restrict__ Wk, const float* __restrict__ bk,
    const float* __restrict__ Wv, const float* __restrict__ bv,
    float* __restrict__ K, float* __restrict__ V, int N) {
  __shared__ float xs[NT * DIM];      // 16 KB
  __shared__ float wks[DIM * 36];     // 18 KB
  __shared__ float wvs[DIM * 36];     // 18 KB
  int base = blockIdx.x * NT;
  int tid = threadIdx.x;
  for (int i = tid; i < NT * (DIM / 4); i += 256)
    ((float4*)xs)[i] = ((const float4*)x)[(size_t)base * (DIM / 4) + i];
  int fg = tid & 31, mg = tid >> 5, m0 = mg * 4;
  float acc[8][4];
#pragma unroll
  for (int k = 0; k < 8; k++)
#pragma unroll
    for (int m = 0; m < 4; m++) acc[k][m] = 0.f;
  for (int p = 0; p < 4; p++) {
    int j0 = p * 32;
    __syncthreads();  // prev panel reads done (also covers xs staging at p=0)
    for (int i = tid; i < DIM * 8; i += 256) {
      int r = i >> 3, c4 = i & 7;
      *(float4*)&wks[r * 36 + c4 * 4] = ((const float4*)Wk)[r * (DIM / 4) + (j0 >> 2) + c4];
      *(float4*)&wvs[r * 36 + c4 * 4] = ((const float4*)Wv)[r * (DIM / 4) + (j0 >> 2) + c4];
    }
    __syncthreads();
    for (int jj = 0; jj < 32; jj += 4) {
      float4 xv[4];
#pragma unroll
      for (int m = 0; m < 4; m++) xv[m] = *(const float4*)&xs[(m0 + m) * DIM + j0 + jj];
#pragma unroll
      for (int k = 0; k < 4; k++) {
        float4 wk4 = *(const float4*)&wks[(fg + 32 * k) * 36 + jj];
        float4 wv4 = *(const float4*)&wvs[(fg + 32 * k) * 36 + jj];
#pragma unroll
        for (int m = 0; m < 4; m++) {
          acc[k][m] += dot4(wk4, xv[m]);
          acc[k + 4][m] += dot4(wv4, xv[m]);
        }
      }
    }
  }
#pragma unroll
  for (int k = 0; k < 4; k++) {
    int f = fg + 32 * k;
    float bkv = bk[f], bvv = bv[f];
#pragma unroll
    for (int m = 0; m < 4; m++) {
      int n = base + m0 + m;
      if (n < N) {
        K[(size_t)n * DIM + f] = acc[k][m] + bkv;
        V[(size_t)n * DIM + f] = acc[k + 4][m] + bvv;
      }
    }
  }
}

// ---------------- CSR build ----------------
__global__ __launch_bounds__(256) void hist_kernel(const int* __restrict__ ei,
                                                   int* __restrict__ cnt, int E) {
  int e = blockIdx.x * 256 + threadIdx.x;
  if (e < E) atomicAdd(&cnt[ei[E + e]], 1);
}

__global__ __launch_bounds__(256) void scanA(const int* __restrict__ cnt,
    int* __restrict__ rs, int* __restrict__ bsum, int N) {
  __shared__ int s[256];
  int t = threadIdx.x;
  int i = blockIdx.x * 256 + t;
  int v = (i < N) ? cnt[i] : 0;
  s[t] = v;
  __syncthreads();
  for (int off = 1; off < 256; off <<= 1) {
    int add = (t >= off) ? s[t - off] : 0;
    __syncthreads();
    s[t] += add;
    __syncthreads();
  }
  if (i < N) rs[i] = s[t] - v;
  if (t == 255) bsum[blockIdx.x] = s[t];
}

__global__ __launch_bounds__(256) void scanB(int* __restrict__ bsum, int nb) {
  __shared__ int s[256];
  int t = threadIdx.x;
  int v = (t < nb) ? bsum[t] : 0;
  s[t] = v;
  __syncthreads();
  for (int off = 1; off < 256; off <<= 1) {
    int add = (t >= off) ? s[t - off] : 0;
    __syncthreads();
    s[t] += add;
    __syncthreads();
  }
  if (t < nb) bsum[t] = s[t] - v;
}

__global__ __launch_bounds__(256) void scanC(int* __restrict__ rs,
    const int* __restrict__ bsum, int* __restrict__ cursor, int N, int E) {
  int i = blockIdx.x * 256 + threadIdx.x;
  if (i < N) {
    int v = rs[i] + bsum[blockIdx.x];
    rs[i] = v;
    cursor[i] = v;
  }
  if (i == 0) rs[N] = E;
}

__global__ __launch_bounds__(256) void scatter_kernel(const int* __restrict__ ei,
    int* __restrict__ cursor, int* __restrict__ esrc, int E) {
  int e = blockIdx.x * 256 + threadIdx.x;
  if (e < E) {
    int d = ei[E + e];
    int pos = atomicAdd(&cursor[d], 1);
    esrc[pos] = ei[e];
  }
}

// ---------------- fused attention aggregate: one wave per dst node ----------
__global__ __launch_bounds__(256) void attn_agg(const float* __restrict__ K,
    const float* __restrict__ V, const float* __restrict__ x,
    const int* __restrict__ rs, const int* __restrict__ esrc,
    float* __restrict__ attn, int N) {
  int wave = threadIdx.x >> 6, lane = threadIdx.x & 63;
  int n = blockIdx.x * 4 + wave;
  if (n >= N) return;
  float2 xv = *(const float2*)&x[n * DIM + 2 * lane];
  int beg = rs[n], end = rs[n + 1];
  float accx = 0.f, accy = 0.f, dloc = 0.f;
  for (int e = beg; e < end; e++) {
    int src = esrc[e];
    float2 kv = *(const float2*)&K[src * DIM + 2 * lane];
    float p = kv.x * xv.x + kv.y * xv.y;
    p += __shfl_xor(p, 1);
    p += __shfl_xor(p, 2);
    p += __shfl_xor(p, 4);
    float ev = expf(p * 0.25f);
    dloc += ev;
    float2 vv = *(const float2*)&V[src * DIM + 2 * lane];
    accx += vv.x * ev;
    accy += vv.y * ev;
  }
  float inv = 1.0f / (dloc + 1e-16f);
  *(float2*)&attn[n * DIM + 2 * lane] = make_float2(accx * inv, accy * inv);
}

// ---------------- O-projection + residual + BN1 stats ----------------
__global__ __launch_bounds__(256) void o_proj_bn(const float* __restrict__ attn,
    const float* __restrict__ x, const float* __restrict__ Wo,
    const float* __restrict__ bo, float* __restrict__ t,
    float* __restrict__ stats, int N) {
  __shared__ float as_[NT * DIM];
  __shared__ float wos[DIM * 36];
  __shared__ float redS[1024];
  __shared__ float redQ[1024];
  int base = blockIdx.x * NT;
  int tid = threadIdx.x;
  for (int i = tid; i < NT * (DIM / 4); i += 256)
    ((float4*)as_)[i] = ((const float4*)attn)[(size_t)base * (DIM / 4) + i];
  int fg = tid & 31, mg = tid >> 5, m0 = mg * 4;
  float acc[4][4];
#pragma unroll
  for (int k = 0; k < 4; k++)
#pragma unroll
    for (int m = 0; m < 4; m++) acc[k][m] = 0.f;
  for (int p = 0; p < 4; p++) {
    int j0 = p * 32;
    __syncthreads();
    for (int i = tid; i < DIM * 8; i += 256) {
      int r = i >> 3, c4 = i & 7;
      *(float4*)&wos[r * 36 + c4 * 4] = ((const float4*)Wo)[r * (DIM / 4) + (j0 >> 2) + c4];
    }
    __syncthreads();
    for (int jj = 0; jj < 32; jj += 4) {
      float4 xv[4];
#pragma unroll
      for (int m = 0; m < 4; m++) xv[m] = *(const float4*)&as_[(m0 + m) * DIM + j0 + jj];
#pragma unroll
      for (int k = 0; k < 4; k++) {
        float4 w = *(const float4*)&wos[(fg + 32 * k) * 36 + jj];
#pragma unroll
        for (int m = 0; m < 4; m++) acc[k][m] += dot4(w, xv[m]);
      }
    }
  }
#pragma unroll
  for (int k = 0; k < 4; k++) {
    int f = fg + 32 * k;
    float b = bo[f];
    float s = 0.f, sq = 0.f;
#pragma unroll
    for (int m = 0; m < 4; m++) {
      int n = base + m0 + m;
      if (n < N) {
        float tv = acc[k][m] + b + x[(size_t)n * DIM + f];
        t[(size_t)n * DIM + f] = tv;
        s += tv;
        sq += tv * tv;
      }
    }
    redS[mg * 128 + f] = s;
    redQ[mg * 128 + f] = sq;
  }
  __syncthreads();
  if (tid < 128) {
    float s = 0.f, sq = 0.f;
#pragma unroll
    for (int g = 0; g < 8; g++) {
      s += redS[g * 128 + tid];
      sq += redQ[g * 128 + tid];
    }
    atomicAdd(&stats[tid], s);
    atomicAdd(&stats[128 + tid], sq);
  }
}

// ---------------- BN finalize ----------------
__global__ void bn_fin(const float* __restrict__ stats, const float* __restrict__ g,
                       const float* __restrict__ b, float* __restrict__ coef,
                       float invN) {
  int f = threadIdx.x;
  float mu = stats[f] * invN;
  float var = stats[128 + f] * invN - mu * mu;
  float a = rsqrtf(var + 1e-5f) * g[f];
  coef[f] = a;
  coef[128 + f] = b[f] - mu * a;
}

// ---------------- FFN stage A: u = relu(BN1(t)@W1^T + b1), u stored fp16 -----
__global__ __launch_bounds__(256) void ffn_a(const float* __restrict__ t,
    const float* __restrict__ coef1, const float* __restrict__ W1,
    const float* __restrict__ b1, _Float16* __restrict__ u, int N) {
  __shared__ float hs[NT * DIM];     // 16 KB
  __shared__ float w1s[256 * 36];    // 36 KB
  int base = blockIdx.x * NT;
  int tid = threadIdx.x;
  for (int i = tid; i < NT * (DIM / 4); i += 256) {
    int f4 = i & 31;
    float4 tv = ((const float4*)t)[(size_t)base * (DIM / 4) + i];
    float4 ca = ((const float4*)coef1)[f4];
    float4 cc = ((const float4*)coef1)[32 + f4];
    float4 hv;
    hv.x = tv.x * ca.x + cc.x;
    hv.y = tv.y * ca.y + cc.y;
    hv.z = tv.z * ca.z + cc.z;
    hv.w = tv.w * ca.w + cc.w;
    ((float4*)hs)[i] = hv;
  }
  int fg = tid & 31, mg = tid >> 5, m0 = mg * 4;
  float acc[8][4];
#pragma unroll
  for (int k = 0; k < 8; k++)
#pragma unroll
    for (int m = 0; m < 4; m++) acc[k][m] = 0.f;
  for (int p = 0; p < 4; p++) {
    int j0 = p * 32;
    __syncthreads();
    for (int i = tid; i < 256 * 8; i += 256) {
      int r = i >> 3, c4 = i & 7;
      *(float4*)&w1s[r * 36 + c4 * 4] = ((const float4*)W1)[r * (DIM / 4) + (j0 >> 2) + c4];
    }
    __syncthreads();
    for (int jj = 0; jj < 32; jj += 4) {
      float4 xv[4];
#pragma unroll
      for (int m = 0; m < 4; m++) xv[m] = *(const float4*)&hs[(m0 + m) * DIM + j0 + jj];
#pragma unroll
      for (int k = 0; k < 8; k++) {
        float4 w = *(const float4*)&w1s[(fg + 32 * k) * 36 + jj];
#pragma unroll
        for (int m = 0; m < 4; m++) acc[k][m] += dot4(w, xv[m]);
      }
    }
  }
#pragma unroll
  for (int k = 0; k < 8; k++) {
    int f = fg + 32 * k;
    float b = b1[f];
#pragma unroll
    for (int m = 0; m < 4; m++) {
      int n = base + m0 + m;
      if (n < N) u[(size_t)n * 256 + f] = (_Float16)fmaxf(acc[k][m] + b, 0.f);
    }
  }
}

// ---------------- FFN stage B: z = BN1(t) + u@W2^T + b2, BN2 stats -----------
__global__ __launch_bounds__(256) void ffn_b(const _Float16* __restrict__ u,
    const float* __restrict__ t, const float* __restrict__ coef1,
    const float* __restrict__ W2, const float* __restrict__ b2,
    float* __restrict__ z, float* __restrict__ stats2, int N) {
  __shared__ float us[NT * 256];     // 32 KB
  __shared__ float wp[DIM * 68];     // 34 KB (64-col panels of W2, stride 68)
  int base = blockIdx.x * NT;
  int tid = threadIdx.x;
  for (int i = tid; i < NT * 64; i += 256) {
    half4 hv = ((const half4*)u)[(size_t)base * 64 + i];
    float4 fv;
    fv.x = (float)hv.x;
    fv.y = (float)hv.y;
    fv.z = (float)hv.z;
    fv.w = (float)hv.w;
    ((float4*)us)[i] = fv;
  }
  int fg = tid & 31, mg = tid >> 5, m0 = mg * 4;
  float acc[4][4];
#pragma unroll
  for (int k = 0; k < 4; k++)
#pragma unroll
    for (int m = 0; m < 4; m++) acc[k][m] = 0.f;
  for (int p = 0; p < 4; p++) {
    int j0 = p * 64;
    __syncthreads();
    for (int i = tid; i < DIM * 16; i += 256) {
      int r = i >> 4, c4 = i & 15;
      *(float4*)&wp[r * 68 + c4 * 4] = ((const float4*)W2)[r * 64 + (j0 >> 2) + c4];
    }
    __syncthreads();
    for (int jj = 0; jj < 64; jj += 4) {
      float4 xv[4];
#pragma unroll
      for (int m = 0; m < 4; m++) xv[m] = *(const float4*)&us[(m0 + m) * 256 + j0 + jj];
#pragma unroll
      for (int k = 0; k < 4; k++) {
        float4 w = *(const float4*)&wp[(fg + 32 * k) * 68 + jj];
#pragma unroll
        for (int m = 0; m < 4; m++) acc[k][m] += dot4(w, xv[m]);
      }
    }
  }
  __syncthreads();  // wp reads done; reuse as reduction buffers
  float* redS = wp;
  float* redQ = wp + 1024;
#pragma unroll
  for (int k = 0; k < 4; k++) {
    int f = fg + 32 * k;
    float b = b2[f];
    float ca = coef1[f], cc = coef1[128 + f];
    float s = 0.f, sq = 0.f;
#pragma unroll
    for (int m = 0; m < 4; m++) {
      int n = base + m0 + m;
      if (n < N) {
        float h = t[(size_t)n * DIM + f] * ca + cc;
        float zv = h + acc[k][m] + b;
        z[(size_t)n * DIM + f] = zv;
        s += zv;
        sq += zv * zv;
      }
    }
    redS[mg * 128 + f] = s;
    redQ[mg * 128 + f] = sq;
  }
  __syncthreads();
  if (tid < 128) {
    float s = 0.f, sq = 0.f;
#pragma unroll
    for (int g = 0; g < 8; g++) {
      s += redS[g * 128 + tid];
      sq += redQ[g * 128 + tid];
    }
    atomicAdd(&stats2[tid], s);
    atomicAdd(&stats2[128 + tid], sq);
  }
}

// ---------------- final BN2 apply ----------------
__global__ __launch_bounds__(256) void final_apply(const float* __restrict__ z,
    const float* __restrict__ coef2, float* __restrict__ out, int total4) {
  int i = blockIdx.x * 256 + threadIdx.x;
  if (i >= total4) return;
  int f = (i * 4) & 127;
  float4 zv = ((const float4*)z)[i];
  float4 o;
  o.x = zv.x * coef2[f] + coef2[128 + f];
  o.y = zv.y * coef2[f + 1] + coef2[128 + f + 1];
  o.z = zv.z * coef2[f + 2] + coef2[128 + f + 2];
  o.w = zv.w * coef2[f + 3] + coef2[128 + f + 3];
  ((float4*)out)[i] = o;
}

extern "C" void kernel_launch(void* const* d_in, const int* in_sizes, int n_in,
                              void* d_out, int out_size, void* d_ws, size_t ws_size,
                              hipStream_t stream) {
  const float* x = (const float*)d_in[0];
  const int* ei = (const int*)d_in[1];
  const float* Wk = (const float*)d_in[2];
  const float* bk = (const float*)d_in[3];
  const float* Wv = (const float*)d_in[4];
  const float* bv = (const float*)d_in[5];
  const float* Wo = (const float*)d_in[6];
  const float* bo = (const float*)d_in[7];
  const float* bn1_g = (const float*)d_in[8];
  const float* bn1_b = (const float*)d_in[9];
  const float* W1 = (const float*)d_in[10];
  const float* b1 = (const float*)d_in[11];
  const float* W2 = (const float*)d_in[12];
  const float* b2 = (const float*)d_in[13];
  const float* bn2_g = (const float*)d_in[14];
  const float* bn2_b = (const float*)d_in[15];
  float* out = (float*)d_out;

  int N = in_sizes[0] / DIM;   // 40000
  int E = in_sizes[1] / 2;     // 640000

  float* Kbuf = (float*)d_ws;
  float* Vbuf = Kbuf + (size_t)N * DIM;
  float* attn = Vbuf + (size_t)N * DIM;
  float* tbuf = Kbuf;                       // reuses K (dead after attn_agg)
  float* zbuf = Vbuf;                       // reuses V
  _Float16* ubuf = (_Float16*)attn;         // reuses attn (dead after o_proj_bn)
  float* stats = attn + (size_t)N * DIM;    // 512 floats: stats1 | stats2
  float* coef = stats + 512;                // 512 floats
  int* cnt = (int*)(coef + 512);
  int* rs = cnt + N;
  int* cursor = rs + N + 1;
  int* esrc = cursor + N;
  int* bsum = esrc + E;

  int nblk = (N + 255) / 256;

  hipMemsetAsync(cnt, 0, (size_t)N * sizeof(int), stream);
  hipMemsetAsync(stats, 0, 512 * sizeof(float), stream);

  kv_proj<<<(N + NT - 1) / NT, 256, 0, stream>>>(x, Wk, bk, Wv, bv, Kbuf, Vbuf, N);
  hist_kernel<<<(E + 255) / 256, 256, 0, stream>>>(ei, cnt, E);
  scanA<<<nblk, 256, 0, stream>>>(cnt, rs, bsum, N);
  scanB<<<1, 256, 0, stream>>>(bsum, nblk);
  scanC<<<nblk, 256, 0, stream>>>(rs, bsum, cursor, N, E);
  scatter_kernel<<<(E + 255) / 256, 256, 0, stream>>>(ei, cursor, esrc, E);
  attn_agg<<<(N + 3) / 4, 256, 0, stream>>>(Kbuf, Vbuf, x, rs, esrc, attn, N);
  o_proj_bn<<<(N + NT - 1) / NT, 256, 0, stream>>>(attn, x, Wo, bo, tbuf, stats, N);
  bn_fin<<<1, 128, 0, stream>>>(stats, bn1_g, bn1_b, coef, 1.0f / N);
  ffn_a<<<(N + NT - 1) / NT, 256, 0, stream>>>(tbuf, coef, W1, b1, ubuf, N);
  ffn_b<<<(N + NT - 1) / NT, 256, 0, stream>>>(ubuf, tbuf, coef, W2, b2, zbuf,
                                               stats + 256, N);
  bn_fin<<<1, 128, 0, stream>>>(stats + 256, bn2_g, bn2_b, coef + 256, 1.0f / N);
  final_apply<<<((N * DIM / 4) + 255) / 256, 256, 0, stream>>>(zbuf, coef + 256, out,
                                                               N * DIM / 4);
}

// Round 4
// 478.998 us; speedup vs baseline: 1.7702x; 1.1099x over previous
//
#include <hip/hip_runtime.h>

#define DIM 128
#define NT 32   // nodes per block for GEMM kernels

typedef __attribute__((ext_vector_type(4))) _Float16 half4;

__device__ __forceinline__ float dot4(float4 a, float4 b) {
  return a.x * b.x + a.y * b.y + a.z * b.z + a.w * b.w;
}

// ---------------- KV projection: K = x@Wk^T+bk, V = x@Wv^T+bv (fp16 out) -----
// Weights staged to LDS in 32-col j-panels, row stride 36 (conflict-free b128).
__global__ __launch_bounds__(256) void kv_proj(const float* __restrict__ x,
    const float* __restrict__ Wk, const float* __restrict__ bk,
    const float* __restrict__ Wv, const float* __restrict__ bv,
    _Float16* __restrict__ K16, _Float16* __restrict__ V16, int N) {
  __shared__ float xs[NT * DIM];      // 16 KB
  __shared__ float wks[DIM * 36];     // 18 KB
  __shared__ float wvs[DIM * 36];     // 18 KB
  int base = blockIdx.x * NT;
  int tid = threadIdx.x;
  for (int i = tid; i < NT * (DIM / 4); i += 256)
    ((float4*)xs)[i] = ((const float4*)x)[(size_t)base * (DIM / 4) + i];
  int fg = tid & 31, mg = tid >> 5, m0 = mg * 4;
  float acc[8][4];
#pragma unroll
  for (int k = 0; k < 8; k++)
#pragma unroll
    for (int m = 0; m < 4; m++) acc[k][m] = 0.f;
  for (int p = 0; p < 4; p++) {
    int j0 = p * 32;
    __syncthreads();  // prev panel reads done (also covers xs staging at p=0)
    for (int i = tid; i < DIM * 8; i += 256) {
      int r = i >> 3, c4 = i & 7;
      *(float4*)&wks[r * 36 + c4 * 4] = ((const float4*)Wk)[r * (DIM / 4) + (j0 >> 2) + c4];
      *(float4*)&wvs[r * 36 + c4 * 4] = ((const float4*)Wv)[r * (DIM / 4) + (j0 >> 2) + c4];
    }
    __syncthreads();
    for (int jj = 0; jj < 32; jj += 4) {
      float4 xv[4];
#pragma unroll
      for (int m = 0; m < 4; m++) xv[m] = *(const float4*)&xs[(m0 + m) * DIM + j0 + jj];
#pragma unroll
      for (int k = 0; k < 4; k++) {
        float4 wk4 = *(const float4*)&wks[(fg + 32 * k) * 36 + jj];
        float4 wv4 = *(const float4*)&wvs[(fg + 32 * k) * 36 + jj];
#pragma unroll
        for (int m = 0; m < 4; m++) {
          acc[k][m] += dot4(wk4, xv[m]);
          acc[k + 4][m] += dot4(wv4, xv[m]);
        }
      }
    }
  }
#pragma unroll
  for (int k = 0; k < 4; k++) {
    int f = fg + 32 * k;
    float bkv = bk[f], bvv = bv[f];
#pragma unroll
    for (int m = 0; m < 4; m++) {
      int n = base + m0 + m;
      if (n < N) {
        K16[(size_t)n * DIM + f] = (_Float16)(acc[k][m] + bkv);
        V16[(size_t)n * DIM + f] = (_Float16)(acc[k + 4][m] + bvv);
      }
    }
  }
}

// ---------------- CSR build ----------------
__global__ __launch_bounds__(256) void hist_kernel(const int* __restrict__ ei,
                                                   int* __restrict__ cnt, int E) {
  int e = blockIdx.x * 256 + threadIdx.x;
  if (e < E) atomicAdd(&cnt[ei[E + e]], 1);
}

__global__ __launch_bounds__(256) void scanA(const int* __restrict__ cnt,
    int* __restrict__ rs, int* __restrict__ bsum, int N) {
  __shared__ int s[256];
  int t = threadIdx.x;
  int i = blockIdx.x * 256 + t;
  int v = (i < N) ? cnt[i] : 0;
  s[t] = v;
  __syncthreads();
  for (int off = 1; off < 256; off <<= 1) {
    int add = (t >= off) ? s[t - off] : 0;
    __syncthreads();
    s[t] += add;
    __syncthreads();
  }
  if (i < N) rs[i] = s[t] - v;
  if (t == 255) bsum[blockIdx.x] = s[t];
}

__global__ __launch_bounds__(256) void scanB(int* __restrict__ bsum, int nb) {
  __shared__ int s[256];
  int t = threadIdx.x;
  int v = (t < nb) ? bsum[t] : 0;
  s[t] = v;
  __syncthreads();
  for (int off = 1; off < 256; off <<= 1) {
    int add = (t >= off) ? s[t - off] : 0;
    __syncthreads();
    s[t] += add;
    __syncthreads();
  }
  if (t < nb) bsum[t] = s[t] - v;
}

__global__ __launch_bounds__(256) void scanC(int* __restrict__ rs,
    const int* __restrict__ bsum, int* __restrict__ cursor, int N, int E) {
  int i = blockIdx.x * 256 + threadIdx.x;
  if (i < N) {
    int v = rs[i] + bsum[blockIdx.x];
    rs[i] = v;
    cursor[i] = v;
  }
  if (i == 0) rs[N] = E;
}

__global__ __launch_bounds__(256) void scatter_kernel(const int* __restrict__ ei,
    int* __restrict__ cursor, int* __restrict__ esrc, int E) {
  int e = blockIdx.x * 256 + threadIdx.x;
  if (e < E) {
    int d = ei[E + e];
    int pos = atomicAdd(&cursor[d], 1);
    esrc[pos] = ei[e];
  }
}

// ---------------- fused attention aggregate: one wave per dst node ----------
// fp16 K/V; two edges in flight per wave (two 32-lane groups), 4 feats/lane.
__global__ __launch_bounds__(256) void attn_agg(const _Float16* __restrict__ K16,
    const _Float16* __restrict__ V16, const float* __restrict__ x,
    const int* __restrict__ rs, const int* __restrict__ esrc,
    float* __restrict__ attn, int N) {
  int wave = threadIdx.x >> 6, lane = threadIdx.x & 63;
  int n = blockIdx.x * 4 + wave;
  if (n >= N) return;
  int l = lane & 31, s = lane >> 5;
  float4 q = *(const float4*)&x[(size_t)n * DIM + 4 * l];  // feats 4l..4l+3
  int beg = rs[n], end = rs[n + 1];
  float a0 = 0.f, a1 = 0.f, a2 = 0.f, a3 = 0.f, dloc = 0.f;
  int e = beg + s;
  int src_next = (e < end) ? esrc[e] : 0;
  while (e < end) {
    int src = src_next;
    int e2 = e + 2;
    src_next = (e2 < end) ? esrc[e2] : 0;
    half4 kh = *(const half4*)&K16[(size_t)src * DIM + 4 * l];
    half4 vh = *(const half4*)&V16[(size_t)src * DIM + 4 * l];
    float p = (float)kh.x * q.x + (float)kh.y * q.y + (float)kh.z * q.z +
              (float)kh.w * q.w;
    p += __shfl_xor(p, 1);
    p += __shfl_xor(p, 2);  // 4-lane cluster = one head (16 feats)
    float ev = __expf(p * 0.25f);
    dloc += ev;
    a0 += ev * (float)vh.x;
    a1 += ev * (float)vh.y;
    a2 += ev * (float)vh.z;
    a3 += ev * (float)vh.w;
    e = e2;
  }
  // merge the two 32-lane groups
  dloc += __shfl_xor(dloc, 32);
  a0 += __shfl_xor(a0, 32);
  a1 += __shfl_xor(a1, 32);
  a2 += __shfl_xor(a2, 32);
  a3 += __shfl_xor(a3, 32);
  if (s == 0) {
    float inv = 1.0f / (dloc + 1e-16f);
    *(float4*)&attn[(size_t)n * DIM + 4 * l] =
        make_float4(a0 * inv, a1 * inv, a2 * inv, a3 * inv);
  }
}

// ---------------- O-projection + residual + BN1 stats ----------------
__global__ __launch_bounds__(256) void o_proj_bn(const float* __restrict__ attn,
    const float* __restrict__ x, const float* __restrict__ Wo,
    const float* __restrict__ bo, float* __restrict__ t,
    float* __restrict__ stats, int N) {
  __shared__ float as_[NT * DIM];
  __shared__ float wos[DIM * 36];
  __shared__ float redS[1024];
  __shared__ float redQ[1024];
  int base = blockIdx.x * NT;
  int tid = threadIdx.x;
  for (int i = tid; i < NT * (DIM / 4); i += 256)
    ((float4*)as_)[i] = ((const float4*)attn)[(size_t)base * (DIM / 4) + i];
  int fg = tid & 31, mg = tid >> 5, m0 = mg * 4;
  float acc[4][4];
#pragma unroll
  for (int k = 0; k < 4; k++)
#pragma unroll
    for (int m = 0; m < 4; m++) acc[k][m] = 0.f;
  for (int p = 0; p < 4; p++) {
    int j0 = p * 32;
    __syncthreads();
    for (int i = tid; i < DIM * 8; i += 256) {
      int r = i >> 3, c4 = i & 7;
      *(float4*)&wos[r * 36 + c4 * 4] = ((const float4*)Wo)[r * (DIM / 4) + (j0 >> 2) + c4];
    }
    __syncthreads();
    for (int jj = 0; jj < 32; jj += 4) {
      float4 xv[4];
#pragma unroll
      for (int m = 0; m < 4; m++) xv[m] = *(const float4*)&as_[(m0 + m) * DIM + j0 + jj];
#pragma unroll
      for (int k = 0; k < 4; k++) {
        float4 w = *(const float4*)&wos[(fg + 32 * k) * 36 + jj];
#pragma unroll
        for (int m = 0; m < 4; m++) acc[k][m] += dot4(w, xv[m]);
      }
    }
  }
#pragma unroll
  for (int k = 0; k < 4; k++) {
    int f = fg + 32 * k;
    float b = bo[f];
    float s = 0.f, sq = 0.f;
#pragma unroll
    for (int m = 0; m < 4; m++) {
      int n = base + m0 + m;
      if (n < N) {
        float tv = acc[k][m] + b + x[(size_t)n * DIM + f];
        t[(size_t)n * DIM + f] = tv;
        s += tv;
        sq += tv * tv;
      }
    }
    redS[mg * 128 + f] = s;
    redQ[mg * 128 + f] = sq;
  }
  __syncthreads();
  if (tid < 128) {
    float s = 0.f, sq = 0.f;
#pragma unroll
    for (int g = 0; g < 8; g++) {
      s += redS[g * 128 + tid];
      sq += redQ[g * 128 + tid];
    }
    atomicAdd(&stats[tid], s);
    atomicAdd(&stats[128 + tid], sq);
  }
}

// ---------------- BN finalize ----------------
__global__ void bn_fin(const float* __restrict__ stats, const float* __restrict__ g,
                       const float* __restrict__ b, float* __restrict__ coef,
                       float invN) {
  int f = threadIdx.x;
  float mu = stats[f] * invN;
  float var = stats[128 + f] * invN - mu * mu;
  float a = rsqrtf(var + 1e-5f) * g[f];
  coef[f] = a;
  coef[128 + f] = b[f] - mu * a;
}

// ---------------- FFN stage A: u = relu(BN1(t)@W1^T + b1), u stored fp16 -----
__global__ __launch_bounds__(256) void ffn_a(const float* __restrict__ t,
    const float* __restrict__ coef1, const float* __restrict__ W1,
    const float* __restrict__ b1, _Float16* __restrict__ u, int N) {
  __shared__ float hs[NT * DIM];     // 16 KB
  __shared__ float w1s[256 * 36];    // 36 KB
  int base = blockIdx.x * NT;
  int tid = threadIdx.x;
  for (int i = tid; i < NT * (DIM / 4); i += 256) {
    int f4 = i & 31;
    float4 tv = ((const float4*)t)[(size_t)base * (DIM / 4) + i];
    float4 ca = ((const float4*)coef1)[f4];
    float4 cc = ((const float4*)coef1)[32 + f4];
    float4 hv;
    hv.x = tv.x * ca.x + cc.x;
    hv.y = tv.y * ca.y + cc.y;
    hv.z = tv.z * ca.z + cc.z;
    hv.w = tv.w * ca.w + cc.w;
    ((float4*)hs)[i] = hv;
  }
  int fg = tid & 31, mg = tid >> 5, m0 = mg * 4;
  float acc[8][4];
#pragma unroll
  for (int k = 0; k < 8; k++)
#pragma unroll
    for (int m = 0; m < 4; m++) acc[k][m] = 0.f;
  for (int p = 0; p < 4; p++) {
    int j0 = p * 32;
    __syncthreads();
    for (int i = tid; i < 256 * 8; i += 256) {
      int r = i >> 3, c4 = i & 7;
      *(float4*)&w1s[r * 36 + c4 * 4] = ((const float4*)W1)[r * (DIM / 4) + (j0 >> 2) + c4];
    }
    __syncthreads();
    for (int jj = 0; jj < 32; jj += 4) {
      float4 xv[4];
#pragma unroll
      for (int m = 0; m < 4; m++) xv[m] = *(const float4*)&hs[(m0 + m) * DIM + j0 + jj];
#pragma unroll
      for (int k = 0; k < 8; k++) {
        float4 w = *(const float4*)&w1s[(fg + 32 * k) * 36 + jj];
#pragma unroll
        for (int m = 0; m < 4; m++) acc[k][m] += dot4(w, xv[m]);
      }
    }
  }
#pragma unroll
  for (int k = 0; k < 8; k++) {
    int f = fg + 32 * k;
    float b = b1[f];
#pragma unroll
    for (int m = 0; m < 4; m++) {
      int n = base + m0 + m;
      if (n < N) u[(size_t)n * 256 + f] = (_Float16)fmaxf(acc[k][m] + b, 0.f);
    }
  }
}

// ---------------- FFN stage B: z = BN1(t) + u@W2^T + b2, BN2 stats -----------
__global__ __launch_bounds__(256) void ffn_b(const _Float16* __restrict__ u,
    const float* __restrict__ t, const float* __restrict__ coef1,
    const float* __restrict__ W2, const float* __restrict__ b2,
    float* __restrict__ z, float* __restrict__ stats2, int N) {
  __shared__ float us[NT * 256];     // 32 KB
  __shared__ float wp[DIM * 68];     // 34 KB (64-col panels of W2, stride 68)
  int base = blockIdx.x * NT;
  int tid = threadIdx.x;
  for (int i = tid; i < NT * 64; i += 256) {
    half4 hv = ((const half4*)u)[(size_t)base * 64 + i];
    float4 fv;
    fv.x = (float)hv.x;
    fv.y = (float)hv.y;
    fv.z = (float)hv.z;
    fv.w = (float)hv.w;
    ((float4*)us)[i] = fv;
  }
  int fg = tid & 31, mg = tid >> 5, m0 = mg * 4;
  float acc[4][4];
#pragma unroll
  for (int k = 0; k < 4; k++)
#pragma unroll
    for (int m = 0; m < 4; m++) acc[k][m] = 0.f;
  for (int p = 0; p < 4; p++) {
    int j0 = p * 64;
    __syncthreads();
    for (int i = tid; i < DIM * 16; i += 256) {
      int r = i >> 4, c4 = i & 15;
      *(float4*)&wp[r * 68 + c4 * 4] = ((const float4*)W2)[r * 64 + (j0 >> 2) + c4];
    }
    __syncthreads();
    for (int jj = 0; jj < 64; jj += 4) {
      float4 xv[4];
#pragma unroll
      for (int m = 0; m < 4; m++) xv[m] = *(const float4*)&us[(m0 + m) * 256 + j0 + jj];
#pragma unroll
      for (int k = 0; k < 4; k++) {
        float4 w = *(const float4*)&wp[(fg + 32 * k) * 68 + jj];
#pragma unroll
        for (int m = 0; m < 4; m++) acc[k][m] += dot4(w, xv[m]);
      }
    }
  }
  __syncthreads();  // wp reads done; reuse as reduction buffers
  float* redS = wp;
  float* redQ = wp + 1024;
#pragma unroll
  for (int k = 0; k < 4; k++) {
    int f = fg + 32 * k;
    float b = b2[f];
    float ca = coef1[f], cc = coef1[128 + f];
    float s = 0.f, sq = 0.f;
#pragma unroll
    for (int m = 0; m < 4; m++) {
      int n = base + m0 + m;
      if (n < N) {
        float h = t[(size_t)n * DIM + f] * ca + cc;
        float zv = h + acc[k][m] + b;
        z[(size_t)n * DIM + f] = zv;
        s += zv;
        sq += zv * zv;
      }
    }
    redS[mg * 128 + f] = s;
    redQ[mg * 128 + f] = sq;
  }
  __syncthreads();
  if (tid < 128) {
    float s = 0.f, sq = 0.f;
#pragma unroll
    for (int g = 0; g < 8; g++) {
      s += redS[g * 128 + tid];
      sq += redQ[g * 128 + tid];
    }
    atomicAdd(&stats2[tid], s);
    atomicAdd(&stats2[128 + tid], sq);
  }
}

// ---------------- final BN2 apply ----------------
__global__ __launch_bounds__(256) void final_apply(const float* __restrict__ z,
    const float* __restrict__ coef2, float* __restrict__ out, int total4) {
  int i = blockIdx.x * 256 + threadIdx.x;
  if (i >= total4) return;
  int f = (i * 4) & 127;
  float4 zv = ((const float4*)z)[i];
  float4 o;
  o.x = zv.x * coef2[f] + coef2[128 + f];
  o.y = zv.y * coef2[f + 1] + coef2[128 + f + 1];
  o.z = zv.z * coef2[f + 2] + coef2[128 + f + 2];
  o.w = zv.w * coef2[f + 3] + coef2[128 + f + 3];
  ((float4*)out)[i] = o;
}

extern "C" void kernel_launch(void* const* d_in, const int* in_sizes, int n_in,
                              void* d_out, int out_size, void* d_ws, size_t ws_size,
                              hipStream_t stream) {
  const float* x = (const float*)d_in[0];
  const int* ei = (const int*)d_in[1];
  const float* Wk = (const float*)d_in[2];
  const float* bk = (const float*)d_in[3];
  const float* Wv = (const float*)d_in[4];
  const float* bv = (const float*)d_in[5];
  const float* Wo = (const float*)d_in[6];
  const float* bo = (const float*)d_in[7];
  const float* bn1_g = (const float*)d_in[8];
  const float* bn1_b = (const float*)d_in[9];
  const float* W1 = (const float*)d_in[10];
  const float* b1 = (const float*)d_in[11];
  const float* W2 = (const float*)d_in[12];
  const float* b2 = (const float*)d_in[13];
  const float* bn2_g = (const float*)d_in[14];
  const float* bn2_b = (const float*)d_in[15];
  float* out = (float*)d_out;

  int N = in_sizes[0] / DIM;   // 40000
  int E = in_sizes[1] / 2;     // 640000

  // workspace layout:
  // [K16|V16: 20 MB] -> reused as tbuf (f32, 20 MB)
  // [attn: 20 MB]    -> reused as zbuf
  // [ubuf: 20 MB fp16]
  // [stats/coef/ints]
  _Float16* K16 = (_Float16*)d_ws;
  _Float16* V16 = K16 + (size_t)N * DIM;
  float* attn = (float*)(V16 + (size_t)N * DIM);
  float* tbuf = (float*)d_ws;               // reuses K16/V16 (dead after attn_agg)
  float* zbuf = attn;                       // reuses attn (dead after o_proj_bn)
  _Float16* ubuf = (_Float16*)(attn + (size_t)N * DIM);
  float* stats = (float*)(ubuf + (size_t)N * 256);  // 512 floats
  float* coef = stats + 512;                        // 512 floats
  int* cnt = (int*)(coef + 512);
  int* rs = cnt + N;
  int* cursor = rs + N + 1;
  int* esrc = cursor + N;
  int* bsum = esrc + E;

  int nblk = (N + 255) / 256;

  hipMemsetAsync(cnt, 0, (size_t)N * sizeof(int), stream);
  hipMemsetAsync(stats, 0, 512 * sizeof(float), stream);

  kv_proj<<<(N + NT - 1) / NT, 256, 0, stream>>>(x, Wk, bk, Wv, bv, K16, V16, N);
  hist_kernel<<<(E + 255) / 256, 256, 0, stream>>>(ei, cnt, E);
  scanA<<<nblk, 256, 0, stream>>>(cnt, rs, bsum, N);
  scanB<<<1, 256, 0, stream>>>(bsum, nblk);
  scanC<<<nblk, 256, 0, stream>>>(rs, bsum, cursor, N, E);
  scatter_kernel<<<(E + 255) / 256, 256, 0, stream>>>(ei, cursor, esrc, E);
  attn_agg<<<(N + 3) / 4, 256, 0, stream>>>(K16, V16, x, rs, esrc, attn, N);
  o_proj_bn<<<(N + NT - 1) / NT, 256, 0, stream>>>(attn, x, Wo, bo, tbuf, stats, N);
  bn_fin<<<1, 128, 0, stream>>>(stats, bn1_g, bn1_b, coef, 1.0f / N);
  ffn_a<<<(N + NT - 1) / NT, 256, 0, stream>>>(tbuf, coef, W1, b1, ubuf, N);
  ffn_b<<<(N + NT - 1) / NT, 256, 0, stream>>>(ubuf, tbuf, coef, W2, b2, zbuf,
                                               stats + 256, N);
  bn_fin<<<1, 128, 0, stream>>>(stats + 256, bn2_g, bn2_b, coef + 256, 1.0f / N);
  final_apply<<<((N * DIM / 4) + 255) / 256, 256, 0, stream>>>(zbuf, coef + 256, out,
                                                               N * DIM / 4);
}

// Round 5
// 380.648 us; speedup vs baseline: 2.2275x; 1.2584x over previous
//
#include <hip/hip_runtime.h>

#define DIM 128
#define NT 32   // nodes per block for VALU GEMM kernels

typedef __attribute__((ext_vector_type(4))) _Float16 half4;
typedef __attribute__((ext_vector_type(8))) _Float16 half8;
typedef __attribute__((ext_vector_type(4))) float f32x4;

#define HP 136  // hs row stride (halfs): 128 + 8 pad
#define UP 264  // us row stride (halfs): 256 + 8 pad

__device__ __forceinline__ float dot4(float4 a, float4 b) {
  return a.x * b.x + a.y * b.y + a.z * b.z + a.w * b.w;
}

// ---------------- fp32 -> fp16 weight conversion (W1, W2) ----------------
__global__ __launch_bounds__(256) void conv_w16(const float* __restrict__ W1,
    const float* __restrict__ W2, _Float16* __restrict__ W1h,
    _Float16* __restrict__ W2h) {
  int i = blockIdx.x * 256 + threadIdx.x;  // 32768 each
  W1h[i] = (_Float16)W1[i];
  W2h[i] = (_Float16)W2[i];
}

// ---------------- KV projection: K = x@Wk^T+bk, V = x@Wv^T+bv (fp16 out) -----
__global__ __launch_bounds__(256) void kv_proj(const float* __restrict__ x,
    const float* __restrict__ Wk, const float* __restrict__ bk,
    const float* __restrict__ Wv, const float* __restrict__ bv,
    _Float16* __restrict__ K16, _Float16* __restrict__ V16, int N) {
  __shared__ float xs[NT * DIM];
  __shared__ float wks[DIM * 36];
  __shared__ float wvs[DIM * 36];
  int base = blockIdx.x * NT;
  int tid = threadIdx.x;
  for (int i = tid; i < NT * (DIM / 4); i += 256)
    ((float4*)xs)[i] = ((const float4*)x)[(size_t)base * (DIM / 4) + i];
  int fg = tid & 31, mg = tid >> 5, m0 = mg * 4;
  float acc[8][4];
#pragma unroll
  for (int k = 0; k < 8; k++)
#pragma unroll
    for (int m = 0; m < 4; m++) acc[k][m] = 0.f;
  for (int p = 0; p < 4; p++) {
    int j0 = p * 32;
    __syncthreads();
    for (int i = tid; i < DIM * 8; i += 256) {
      int r = i >> 3, c4 = i & 7;
      *(float4*)&wks[r * 36 + c4 * 4] = ((const float4*)Wk)[r * (DIM / 4) + (j0 >> 2) + c4];
      *(float4*)&wvs[r * 36 + c4 * 4] = ((const float4*)Wv)[r * (DIM / 4) + (j0 >> 2) + c4];
    }
    __syncthreads();
    for (int jj = 0; jj < 32; jj += 4) {
      float4 xv[4];
#pragma unroll
      for (int m = 0; m < 4; m++) xv[m] = *(const float4*)&xs[(m0 + m) * DIM + j0 + jj];
#pragma unroll
      for (int k = 0; k < 4; k++) {
        float4 wk4 = *(const float4*)&wks[(fg + 32 * k) * 36 + jj];
        float4 wv4 = *(const float4*)&wvs[(fg + 32 * k) * 36 + jj];
#pragma unroll
        for (int m = 0; m < 4; m++) {
          acc[k][m] += dot4(wk4, xv[m]);
          acc[k + 4][m] += dot4(wv4, xv[m]);
        }
      }
    }
  }
#pragma unroll
  for (int k = 0; k < 4; k++) {
    int f = fg + 32 * k;
    float bkv = bk[f], bvv = bv[f];
#pragma unroll
    for (int m = 0; m < 4; m++) {
      int n = base + m0 + m;
      if (n < N) {
        K16[(size_t)n * DIM + f] = (_Float16)(acc[k][m] + bkv);
        V16[(size_t)n * DIM + f] = (_Float16)(acc[k + 4][m] + bvv);
      }
    }
  }
}

// ---------------- CSR build ----------------
__global__ __launch_bounds__(256) void hist_kernel(const int* __restrict__ ei,
                                                   int* __restrict__ cnt, int E) {
  int e = blockIdx.x * 256 + threadIdx.x;
  if (e < E) atomicAdd(&cnt[ei[E + e]], 1);
}

__global__ __launch_bounds__(256) void scanA(const int* __restrict__ cnt,
    int* __restrict__ rs, int* __restrict__ bsum, int N) {
  __shared__ int s[256];
  int t = threadIdx.x;
  int i = blockIdx.x * 256 + t;
  int v = (i < N) ? cnt[i] : 0;
  s[t] = v;
  __syncthreads();
  for (int off = 1; off < 256; off <<= 1) {
    int add = (t >= off) ? s[t - off] : 0;
    __syncthreads();
    s[t] += add;
    __syncthreads();
  }
  if (i < N) rs[i] = s[t] - v;
  if (t == 255) bsum[blockIdx.x] = s[t];
}

__global__ __launch_bounds__(256) void scanB(int* __restrict__ bsum, int nb) {
  __shared__ int s[256];
  int t = threadIdx.x;
  int v = (t < nb) ? bsum[t] : 0;
  s[t] = v;
  __syncthreads();
  for (int off = 1; off < 256; off <<= 1) {
    int add = (t >= off) ? s[t - off] : 0;
    __syncthreads();
    s[t] += add;
    __syncthreads();
  }
  if (t < nb) bsum[t] = s[t] - v;
}

__global__ __launch_bounds__(256) void scanC(int* __restrict__ rs,
    const int* __restrict__ bsum, int* __restrict__ cursor, int N, int E) {
  int i = blockIdx.x * 256 + threadIdx.x;
  if (i < N) {
    int v = rs[i] + bsum[blockIdx.x];
    rs[i] = v;
    cursor[i] = v;
  }
  if (i == 0) rs[N] = E;
}

__global__ __launch_bounds__(256) void scatter_kernel(const int* __restrict__ ei,
    int* __restrict__ cursor, int* __restrict__ esrc, int E) {
  int e = blockIdx.x * 256 + threadIdx.x;
  if (e < E) {
    int d = ei[E + e];
    int pos = atomicAdd(&cursor[d], 1);
    esrc[pos] = ei[e];
  }
}

// ---------------- fused attention aggregate: one wave per dst node ----------
__global__ __launch_bounds__(256) void attn_agg(const _Float16* __restrict__ K16,
    const _Float16* __restrict__ V16, const float* __restrict__ x,
    const int* __restrict__ rs, const int* __restrict__ esrc,
    float* __restrict__ attn, int N) {
  int wave = threadIdx.x >> 6, lane = threadIdx.x & 63;
  int n = blockIdx.x * 4 + wave;
  if (n >= N) return;
  int l = lane & 31, s = lane >> 5;
  float4 q = *(const float4*)&x[(size_t)n * DIM + 4 * l];
  int beg = rs[n], end = rs[n + 1];
  float a0 = 0.f, a1 = 0.f, a2 = 0.f, a3 = 0.f, dloc = 0.f;
  int e = beg + s;
  int src_next = (e < end) ? esrc[e] : 0;
  while (e < end) {
    int src = src_next;
    int e2 = e + 2;
    src_next = (e2 < end) ? esrc[e2] : 0;
    half4 kh = *(const half4*)&K16[(size_t)src * DIM + 4 * l];
    half4 vh = *(const half4*)&V16[(size_t)src * DIM + 4 * l];
    float p = (float)kh.x * q.x + (float)kh.y * q.y + (float)kh.z * q.z +
              (float)kh.w * q.w;
    p += __shfl_xor(p, 1);
    p += __shfl_xor(p, 2);
    float ev = __expf(p * 0.25f);
    dloc += ev;
    a0 += ev * (float)vh.x;
    a1 += ev * (float)vh.y;
    a2 += ev * (float)vh.z;
    a3 += ev * (float)vh.w;
    e = e2;
  }
  dloc += __shfl_xor(dloc, 32);
  a0 += __shfl_xor(a0, 32);
  a1 += __shfl_xor(a1, 32);
  a2 += __shfl_xor(a2, 32);
  a3 += __shfl_xor(a3, 32);
  if (s == 0) {
    float inv = 1.0f / (dloc + 1e-16f);
    *(float4*)&attn[(size_t)n * DIM + 4 * l] =
        make_float4(a0 * inv, a1 * inv, a2 * inv, a3 * inv);
  }
}

// ---------------- O-projection + residual + BN1 stats ----------------
__global__ __launch_bounds__(256) void o_proj_bn(const float* __restrict__ attn,
    const float* __restrict__ x, const float* __restrict__ Wo,
    const float* __restrict__ bo, float* __restrict__ t,
    float* __restrict__ stats, int N) {
  __shared__ float as_[NT * DIM];
  __shared__ float wos[DIM * 36];
  __shared__ float redS[1024];
  __shared__ float redQ[1024];
  int base = blockIdx.x * NT;
  int tid = threadIdx.x;
  for (int i = tid; i < NT * (DIM / 4); i += 256)
    ((float4*)as_)[i] = ((const float4*)attn)[(size_t)base * (DIM / 4) + i];
  int fg = tid & 31, mg = tid >> 5, m0 = mg * 4;
  float acc[4][4];
#pragma unroll
  for (int k = 0; k < 4; k++)
#pragma unroll
    for (int m = 0; m < 4; m++) acc[k][m] = 0.f;
  for (int p = 0; p < 4; p++) {
    int j0 = p * 32;
    __syncthreads();
    for (int i = tid; i < DIM * 8; i += 256) {
      int r = i >> 3, c4 = i & 7;
      *(float4*)&wos[r * 36 + c4 * 4] = ((const float4*)Wo)[r * (DIM / 4) + (j0 >> 2) + c4];
    }
    __syncthreads();
    for (int jj = 0; jj < 32; jj += 4) {
      float4 xv[4];
#pragma unroll
      for (int m = 0; m < 4; m++) xv[m] = *(const float4*)&as_[(m0 + m) * DIM + j0 + jj];
#pragma unroll
      for (int k = 0; k < 4; k++) {
        float4 w = *(const float4*)&wos[(fg + 32 * k) * 36 + jj];
#pragma unroll
        for (int m = 0; m < 4; m++) acc[k][m] += dot4(w, xv[m]);
      }
    }
  }
#pragma unroll
  for (int k = 0; k < 4; k++) {
    int f = fg + 32 * k;
    float b = bo[f];
    float s = 0.f, sq = 0.f;
#pragma unroll
    for (int m = 0; m < 4; m++) {
      int n = base + m0 + m;
      if (n < N) {
        float tv = acc[k][m] + b + x[(size_t)n * DIM + f];
        t[(size_t)n * DIM + f] = tv;
        s += tv;
        sq += tv * tv;
      }
    }
    redS[mg * 128 + f] = s;
    redQ[mg * 128 + f] = sq;
  }
  __syncthreads();
  if (tid < 128) {
    float s = 0.f, sq = 0.f;
#pragma unroll
    for (int g = 0; g < 8; g++) {
      s += redS[g * 128 + tid];
      sq += redQ[g * 128 + tid];
    }
    atomicAdd(&stats[tid], s);
    atomicAdd(&stats[128 + tid], sq);
  }
}

// ---------------- BN finalize ----------------
__global__ void bn_fin(const float* __restrict__ stats, const float* __restrict__ g,
                       const float* __restrict__ b, float* __restrict__ coef,
                       float invN) {
  int f = threadIdx.x;
  float mu = stats[f] * invN;
  float var = stats[128 + f] * invN - mu * mu;
  float a = rsqrtf(var + 1e-5f) * g[f];
  coef[f] = a;
  coef[128 + f] = b[f] - mu * a;
}

// ---------------- fused FFN via MFMA (fp16 in, fp32 acc) --------------------
// z = h + relu(h@W1^T+b1)@W2^T + b2,  h = BN1(t);  also BN2 stats.
// Block = 4 waves, 64 nodes (N=40000 = 625*64 exactly).
// MFMA convention (m89/m120-verified): A/B per-lane [idx=lane&15][k=quad*8+j],
// D = A·B^T in C-layout (col=lane&15, row=quad*4+reg).
__global__ __launch_bounds__(256) void ffn_mfma(const float* __restrict__ t,
    const float* __restrict__ coef1, const _Float16* __restrict__ W1h,
    const float* __restrict__ b1, const _Float16* __restrict__ W2h,
    const float* __restrict__ b2, float* __restrict__ z,
    float* __restrict__ stats2, int N) {
  __shared__ _Float16 hs[64 * HP];  // 17.4 KB, h tile [m][k], pad 8
  __shared__ _Float16 us[64 * UP];  // 33.8 KB, u tile [m][k2], pad 8
  int tid = threadIdx.x;
  int base = blockIdx.x * 64;
  int lane = tid & 63, w = tid >> 6;
  int l15 = lane & 15, quad = lane >> 4;

  // ---- stage h = BN1(t) as fp16, [m][k] ----
  for (int i = tid; i < 64 * 32; i += 256) {
    int m = i >> 5, c4 = i & 31;
    float4 tv = ((const float4*)t)[(size_t)(base + m) * 32 + c4];
    float4 ca = ((const float4*)coef1)[c4];
    float4 cc = ((const float4*)coef1)[32 + c4];
    half4 hv;
    hv.x = (_Float16)(tv.x * ca.x + cc.x);
    hv.y = (_Float16)(tv.y * ca.y + cc.y);
    hv.z = (_Float16)(tv.z * ca.z + cc.z);
    hv.w = (_Float16)(tv.w * ca.w + cc.w);
    *(half4*)&hs[m * HP + c4 * 4] = hv;
  }
  __syncthreads();

  // ---- GEMM1: u = relu(h@W1^T + b1); wave w owns outs [w*64, w*64+64) ----
  int n0 = w * 64;
  half8 afr[4][4];  // [mtile][kstep]
#pragma unroll
  for (int mt = 0; mt < 4; mt++)
#pragma unroll
    for (int ks = 0; ks < 4; ks++)
      afr[mt][ks] = *(const half8*)&hs[(mt * 16 + l15) * HP + ks * 32 + quad * 8];

#pragma unroll
  for (int nt = 0; nt < 4; nt++) {
    int n = n0 + nt * 16 + l15;
    half8 bfr[4];
#pragma unroll
    for (int ks = 0; ks < 4; ks++)
      bfr[ks] = *(const half8*)&W1h[(size_t)n * 128 + ks * 32 + quad * 8];
    f32x4 acc[4];
#pragma unroll
    for (int mt = 0; mt < 4; mt++) acc[mt] = (f32x4){0.f, 0.f, 0.f, 0.f};
#pragma unroll
    for (int ks = 0; ks < 4; ks++)
#pragma unroll
      for (int mt = 0; mt < 4; mt++)
        acc[mt] = __builtin_amdgcn_mfma_f32_16x16x32_f16(afr[mt][ks], bfr[ks],
                                                          acc[mt], 0, 0, 0);
    float bias = b1[n];
#pragma unroll
    for (int mt = 0; mt < 4; mt++)
#pragma unroll
      for (int r = 0; r < 4; r++)
        us[(mt * 16 + quad * 4 + r) * UP + n] =
            (_Float16)fmaxf(acc[mt][r] + bias, 0.f);
  }
  __syncthreads();

  // ---- GEMM2: z = h + u@W2^T + b2; wave w owns outs [w*32, w*32+32) ----
  int n2 = w * 32;
  f32x4 acc2[4][2];
#pragma unroll
  for (int mt = 0; mt < 4; mt++)
#pragma unroll
    for (int nt = 0; nt < 2; nt++) acc2[mt][nt] = (f32x4){0.f, 0.f, 0.f, 0.f};
  for (int ks = 0; ks < 8; ks++) {
    half8 a[4], b[2];
#pragma unroll
    for (int mt = 0; mt < 4; mt++)
      a[mt] = *(const half8*)&us[(mt * 16 + l15) * UP + ks * 32 + quad * 8];
#pragma unroll
    for (int nt = 0; nt < 2; nt++)
      b[nt] = *(const half8*)&W2h[(size_t)(n2 + nt * 16 + l15) * 256 + ks * 32 +
                                  quad * 8];
#pragma unroll
    for (int mt = 0; mt < 4; mt++)
#pragma unroll
      for (int nt = 0; nt < 2; nt++)
        acc2[mt][nt] =
            __builtin_amdgcn_mfma_f32_16x16x32_f16(a[mt], b[nt], acc2[mt][nt], 0, 0, 0);
  }

  // ---- epilogue: residual + store + BN2 stats ----
#pragma unroll
  for (int nt = 0; nt < 2; nt++) {
    int f = n2 + nt * 16 + l15;
    float bz = b2[f];
    float s = 0.f, q = 0.f;
#pragma unroll
    for (int mt = 0; mt < 4; mt++) {
#pragma unroll
      for (int r = 0; r < 4; r++) {
        int row = mt * 16 + quad * 4 + r;
        float hv = (float)hs[row * HP + f];
        float zv = hv + acc2[mt][nt][r] + bz;
        z[(size_t)(base + row) * DIM + f] = zv;
        s += zv;
        q += zv * zv;
      }
    }
    s += __shfl_xor(s, 16);
    s += __shfl_xor(s, 32);
    q += __shfl_xor(q, 16);
    q += __shfl_xor(q, 32);
    if (quad == 0) {
      atomicAdd(&stats2[f], s);
      atomicAdd(&stats2[128 + f], q);
    }
  }
}

// ---------------- final BN2 apply ----------------
__global__ __launch_bounds__(256) void final_apply(const float* __restrict__ z,
    const float* __restrict__ coef2, float* __restrict__ out, int total4) {
  int i = blockIdx.x * 256 + threadIdx.x;
  if (i >= total4) return;
  int f = (i * 4) & 127;
  float4 zv = ((const float4*)z)[i];
  float4 o;
  o.x = zv.x * coef2[f] + coef2[128 + f];
  o.y = zv.y * coef2[f + 1] + coef2[128 + f + 1];
  o.z = zv.z * coef2[f + 2] + coef2[128 + f + 2];
  o.w = zv.w * coef2[f + 3] + coef2[128 + f + 3];
  ((float4*)out)[i] = o;
}

extern "C" void kernel_launch(void* const* d_in, const int* in_sizes, int n_in,
                              void* d_out, int out_size, void* d_ws, size_t ws_size,
                              hipStream_t stream) {
  const float* x = (const float*)d_in[0];
  const int* ei = (const int*)d_in[1];
  const float* Wk = (const float*)d_in[2];
  const float* bk = (const float*)d_in[3];
  const float* Wv = (const float*)d_in[4];
  const float* bv = (const float*)d_in[5];
  const float* Wo = (const float*)d_in[6];
  const float* bo = (const float*)d_in[7];
  const float* bn1_g = (const float*)d_in[8];
  const float* bn1_b = (const float*)d_in[9];
  const float* W1 = (const float*)d_in[10];
  const float* b1 = (const float*)d_in[11];
  const float* W2 = (const float*)d_in[12];
  const float* b2 = (const float*)d_in[13];
  const float* bn2_g = (const float*)d_in[14];
  const float* bn2_b = (const float*)d_in[15];
  float* out = (float*)d_out;

  int N = in_sizes[0] / DIM;   // 40000
  int E = in_sizes[1] / 2;     // 640000

  // workspace layout:
  // [K16|V16: 20.5 MB fp16] -> reused as tbuf (f32)
  // [attn: 20.5 MB f32]     -> reused as zbuf
  // [W1h 64KB | W2h 64KB fp16] [stats 2KB] [coef 2KB] [ints]
  _Float16* K16 = (_Float16*)d_ws;
  _Float16* V16 = K16 + (size_t)N * DIM;
  float* attn = (float*)(V16 + (size_t)N * DIM);
  float* tbuf = (float*)d_ws;               // reuses K16/V16 (dead after attn_agg)
  float* zbuf = attn;                       // reuses attn (dead after o_proj_bn)
  _Float16* W1h = (_Float16*)(attn + (size_t)N * DIM);
  _Float16* W2h = W1h + 32768;
  float* stats = (float*)(W2h + 32768);     // 512 floats: stats1 | stats2
  float* coef = stats + 512;                // 512 floats
  int* cnt = (int*)(coef + 512);
  int* rs = cnt + N;
  int* cursor = rs + N + 1;
  int* esrc = cursor + N;
  int* bsum = esrc + E;

  int nblk = (N + 255) / 256;

  hipMemsetAsync(cnt, 0, (size_t)N * sizeof(int), stream);
  hipMemsetAsync(stats, 0, 512 * sizeof(float), stream);

  conv_w16<<<128, 256, 0, stream>>>(W1, W2, W1h, W2h);
  kv_proj<<<(N + NT - 1) / NT, 256, 0, stream>>>(x, Wk, bk, Wv, bv, K16, V16, N);
  hist_kernel<<<(E + 255) / 256, 256, 0, stream>>>(ei, cnt, E);
  scanA<<<nblk, 256, 0, stream>>>(cnt, rs, bsum, N);
  scanB<<<1, 256, 0, stream>>>(bsum, nblk);
  scanC<<<nblk, 256, 0, stream>>>(rs, bsum, cursor, N, E);
  scatter_kernel<<<(E + 255) / 256, 256, 0, stream>>>(ei, cursor, esrc, E);
  attn_agg<<<(N + 3) / 4, 256, 0, stream>>>(K16, V16, x, rs, esrc, attn, N);
  o_proj_bn<<<(N + NT - 1) / NT, 256, 0, stream>>>(attn, x, Wo, bo, tbuf, stats, N);
  bn_fin<<<1, 128, 0, stream>>>(stats, bn1_g, bn1_b, coef, 1.0f / N);
  ffn_mfma<<<N / 64, 256, 0, stream>>>(tbuf, coef, W1h, b1, W2h, b2, zbuf,
                                       stats + 256, N);
  bn_fin<<<1, 128, 0, stream>>>(stats + 256, bn2_g, bn2_b, coef + 256, 1.0f / N);
  final_apply<<<((N * DIM / 4) + 255) / 256, 256, 0, stream>>>(zbuf, coef + 256, out,
                                                               N * DIM / 4);
}

// Round 6
// 307.404 us; speedup vs baseline: 2.7583x; 1.2383x over previous
//
#include <hip/hip_runtime.h>

#define DIM 128

typedef __attribute__((ext_vector_type(4))) _Float16 half4;
typedef __attribute__((ext_vector_type(8))) _Float16 half8;
typedef __attribute__((ext_vector_type(4))) float f32x4;

#define HP 136  // fp16 tile row stride (halfs): 128 + 8 pad (2-way = free)
#define UP 264  // fp16 tile row stride (halfs): 256 + 8 pad

// ---------------- fp32 -> fp16 conversion of all weights ----------------
__global__ __launch_bounds__(256) void conv_wall(const float* __restrict__ Wk,
    const float* __restrict__ Wv, const float* __restrict__ Wo,
    const float* __restrict__ W1, const float* __restrict__ W2,
    _Float16* __restrict__ Wkh, _Float16* __restrict__ Wvh,
    _Float16* __restrict__ Woh, _Float16* __restrict__ W1h,
    _Float16* __restrict__ W2h) {
  int i = blockIdx.x * 256 + threadIdx.x;  // 114688 total
  if (i < 16384) Wkh[i] = (_Float16)Wk[i];
  else if (i < 32768) Wvh[i - 16384] = (_Float16)Wv[i - 16384];
  else if (i < 49152) Woh[i - 32768] = (_Float16)Wo[i - 32768];
  else if (i < 81920) W1h[i - 49152] = (_Float16)W1[i - 49152];
  else W2h[i - 81920] = (_Float16)W2[i - 81920];
}

// ---------------- KV projection via MFMA -------------------------------------
// Block = 64 nodes, 4 waves. Waves 0-1 -> K (Wk), waves 2-3 -> V (Wv);
// wave handles 64 output feats = (w&1)*64 .. +64. 64 MFMAs/wave.
__global__ __launch_bounds__(256) void kv_mfma(const float* __restrict__ x,
    const _Float16* __restrict__ Wkh, const float* __restrict__ bk,
    const _Float16* __restrict__ Wvh, const float* __restrict__ bv,
    _Float16* __restrict__ K16, _Float16* __restrict__ V16, int N) {
  __shared__ _Float16 xs[64 * HP];  // 17.4 KB
  int tid = threadIdx.x;
  int base = blockIdx.x * 64;
  int lane = tid & 63, w = tid >> 6;
  int l15 = lane & 15, quad = lane >> 4;

  for (int i = tid; i < 64 * 32; i += 256) {
    int m = i >> 5, c4 = i & 31;
    float4 tv = ((const float4*)x)[(size_t)(base + m) * 32 + c4];
    half4 hv;
    hv.x = (_Float16)tv.x; hv.y = (_Float16)tv.y;
    hv.z = (_Float16)tv.z; hv.w = (_Float16)tv.w;
    *(half4*)&xs[m * HP + c4 * 4] = hv;
  }
  __syncthreads();

  half8 afr[4][4];
#pragma unroll
  for (int mt = 0; mt < 4; mt++)
#pragma unroll
    for (int ks = 0; ks < 4; ks++)
      afr[mt][ks] = *(const half8*)&xs[(mt * 16 + l15) * HP + ks * 32 + quad * 8];

  const _Float16* W = (w < 2) ? Wkh : Wvh;
  const float* bias = (w < 2) ? bk : bv;
  _Float16* O = (w < 2) ? K16 : V16;
  int c0 = (w & 1) * 64;

#pragma unroll
  for (int nt = 0; nt < 4; nt++) {
    int f = c0 + nt * 16 + l15;
    half8 bfr[4];
#pragma unroll
    for (int ks = 0; ks < 4; ks++)
      bfr[ks] = *(const half8*)&W[(size_t)f * 128 + ks * 32 + quad * 8];
    f32x4 acc[4];
#pragma unroll
    for (int mt = 0; mt < 4; mt++) acc[mt] = (f32x4){0.f, 0.f, 0.f, 0.f};
#pragma unroll
    for (int ks = 0; ks < 4; ks++)
#pragma unroll
      for (int mt = 0; mt < 4; mt++)
        acc[mt] = __builtin_amdgcn_mfma_f32_16x16x32_f16(afr[mt][ks], bfr[ks],
                                                          acc[mt], 0, 0, 0);
    float bb = bias[f];
#pragma unroll
    for (int mt = 0; mt < 4; mt++)
#pragma unroll
      for (int r = 0; r < 4; r++)
        O[(size_t)(base + mt * 16 + quad * 4 + r) * DIM + f] =
            (_Float16)(acc[mt][r] + bb);
  }
}

// ---------------- CSR build ----------------
__global__ __launch_bounds__(256) void hist_kernel(const int* __restrict__ ei,
                                                   int* __restrict__ cnt, int E) {
  int e = blockIdx.x * 256 + threadIdx.x;
  if (e < E) atomicAdd(&cnt[ei[E + e]], 1);
}

__global__ __launch_bounds__(256) void scanA(const int* __restrict__ cnt,
    int* __restrict__ rs, int* __restrict__ bsum, int N) {
  __shared__ int s[256];
  int t = threadIdx.x;
  int i = blockIdx.x * 256 + t;
  int v = (i < N) ? cnt[i] : 0;
  s[t] = v;
  __syncthreads();
  for (int off = 1; off < 256; off <<= 1) {
    int add = (t >= off) ? s[t - off] : 0;
    __syncthreads();
    s[t] += add;
    __syncthreads();
  }
  if (i < N) rs[i] = s[t] - v;
  if (t == 255) bsum[blockIdx.x] = s[t];
}

__global__ __launch_bounds__(256) void scanB(int* __restrict__ bsum, int nb) {
  __shared__ int s[256];
  int t = threadIdx.x;
  int v = (t < nb) ? bsum[t] : 0;
  s[t] = v;
  __syncthreads();
  for (int off = 1; off < 256; off <<= 1) {
    int add = (t >= off) ? s[t - off] : 0;
    __syncthreads();
    s[t] += add;
    __syncthreads();
  }
  if (t < nb) bsum[t] = s[t] - v;
}

__global__ __launch_bounds__(256) void scanC(int* __restrict__ rs,
    const int* __restrict__ bsum, int* __restrict__ cursor, int N, int E) {
  int i = blockIdx.x * 256 + threadIdx.x;
  if (i < N) {
    int v = rs[i] + bsum[blockIdx.x];
    rs[i] = v;
    cursor[i] = v;
  }
  if (i == 0) rs[N] = E;
}

__global__ __launch_bounds__(256) void scatter_kernel(const int* __restrict__ ei,
    int* __restrict__ cursor, int* __restrict__ esrc, int E) {
  int e = blockIdx.x * 256 + threadIdx.x;
  if (e < E) {
    int d = ei[E + e];
    int pos = atomicAdd(&cursor[d], 1);
    esrc[pos] = ei[e];
  }
}

// ---------------- fused attention aggregate: one wave per dst node ----------
__global__ __launch_bounds__(256) void attn_agg(const _Float16* __restrict__ K16,
    const _Float16* __restrict__ V16, const float* __restrict__ x,
    const int* __restrict__ rs, const int* __restrict__ esrc,
    float* __restrict__ attn, int N) {
  int wave = threadIdx.x >> 6, lane = threadIdx.x & 63;
  int n = blockIdx.x * 4 + wave;
  if (n >= N) return;
  int l = lane & 31, s = lane >> 5;
  float4 q = *(const float4*)&x[(size_t)n * DIM + 4 * l];
  int beg = rs[n], end = rs[n + 1];
  float a0 = 0.f, a1 = 0.f, a2 = 0.f, a3 = 0.f, dloc = 0.f;
  int e = beg + s;
  int src_next = (e < end) ? esrc[e] : 0;
  while (e < end) {
    int src = src_next;
    int e2 = e + 2;
    src_next = (e2 < end) ? esrc[e2] : 0;
    half4 kh = *(const half4*)&K16[(size_t)src * DIM + 4 * l];
    half4 vh = *(const half4*)&V16[(size_t)src * DIM + 4 * l];
    float p = (float)kh.x * q.x + (float)kh.y * q.y + (float)kh.z * q.z +
              (float)kh.w * q.w;
    p += __shfl_xor(p, 1);
    p += __shfl_xor(p, 2);
    float ev = __expf(p * 0.25f);
    dloc += ev;
    a0 += ev * (float)vh.x;
    a1 += ev * (float)vh.y;
    a2 += ev * (float)vh.z;
    a3 += ev * (float)vh.w;
    e = e2;
  }
  dloc += __shfl_xor(dloc, 32);
  a0 += __shfl_xor(a0, 32);
  a1 += __shfl_xor(a1, 32);
  a2 += __shfl_xor(a2, 32);
  a3 += __shfl_xor(a3, 32);
  if (s == 0) {
    float inv = 1.0f / (dloc + 1e-16f);
    *(float4*)&attn[(size_t)n * DIM + 4 * l] =
        make_float4(a0 * inv, a1 * inv, a2 * inv, a3 * inv);
  }
}

// ---------------- O-projection via MFMA + residual + BN1 stats ---------------
// Block = 64 nodes, 4 waves; wave owns 32 output feats. 32 MFMAs/wave.
__global__ __launch_bounds__(256) void o_proj_mfma(const float* __restrict__ attn,
    const float* __restrict__ x, const _Float16* __restrict__ Woh,
    const float* __restrict__ bo, float* __restrict__ t,
    float* __restrict__ stats, int N) {
  __shared__ _Float16 as16[64 * HP];  // 17.4 KB
  int tid = threadIdx.x;
  int base = blockIdx.x * 64;
  int lane = tid & 63, w = tid >> 6;
  int l15 = lane & 15, quad = lane >> 4;

  for (int i = tid; i < 64 * 32; i += 256) {
    int m = i >> 5, c4 = i & 31;
    float4 tv = ((const float4*)attn)[(size_t)(base + m) * 32 + c4];
    half4 hv;
    hv.x = (_Float16)tv.x; hv.y = (_Float16)tv.y;
    hv.z = (_Float16)tv.z; hv.w = (_Float16)tv.w;
    *(half4*)&as16[m * HP + c4 * 4] = hv;
  }
  __syncthreads();

  half8 afr[4][4];
#pragma unroll
  for (int mt = 0; mt < 4; mt++)
#pragma unroll
    for (int ks = 0; ks < 4; ks++)
      afr[mt][ks] = *(const half8*)&as16[(mt * 16 + l15) * HP + ks * 32 + quad * 8];

  int c0 = w * 32;
  f32x4 acc[4][2];
#pragma unroll
  for (int mt = 0; mt < 4; mt++)
#pragma unroll
    for (int nt = 0; nt < 2; nt++) acc[mt][nt] = (f32x4){0.f, 0.f, 0.f, 0.f};
#pragma unroll
  for (int ks = 0; ks < 4; ks++) {
    half8 b[2];
#pragma unroll
    for (int nt = 0; nt < 2; nt++)
      b[nt] = *(const half8*)&Woh[(size_t)(c0 + nt * 16 + l15) * 128 + ks * 32 +
                                  quad * 8];
#pragma unroll
    for (int mt = 0; mt < 4; mt++)
#pragma unroll
      for (int nt = 0; nt < 2; nt++)
        acc[mt][nt] =
            __builtin_amdgcn_mfma_f32_16x16x32_f16(afr[mt][ks], b[nt], acc[mt][nt], 0, 0, 0);
  }

#pragma unroll
  for (int nt = 0; nt < 2; nt++) {
    int f = c0 + nt * 16 + l15;
    float bb = bo[f];
    float s = 0.f, q = 0.f;
#pragma unroll
    for (int mt = 0; mt < 4; mt++) {
#pragma unroll
      for (int r = 0; r < 4; r++) {
        int row = mt * 16 + quad * 4 + r;
        float tv = acc[mt][nt][r] + bb + x[(size_t)(base + row) * DIM + f];
        t[(size_t)(base + row) * DIM + f] = tv;
        s += tv;
        q += tv * tv;
      }
    }
    s += __shfl_xor(s, 16);
    s += __shfl_xor(s, 32);
    q += __shfl_xor(q, 16);
    q += __shfl_xor(q, 32);
    if (quad == 0) {
      atomicAdd(&stats[f], s);
      atomicAdd(&stats[128 + f], q);
    }
  }
}

// ---------------- BN finalize ----------------
__global__ void bn_fin(const float* __restrict__ stats, const float* __restrict__ g,
                       const float* __restrict__ b, float* __restrict__ coef,
                       float invN) {
  int f = threadIdx.x;
  float mu = stats[f] * invN;
  float var = stats[128 + f] * invN - mu * mu;
  float a = rsqrtf(var + 1e-5f) * g[f];
  coef[f] = a;
  coef[128 + f] = b[f] - mu * a;
}

// ---------------- fused FFN via MFMA (fp16 in, fp32 acc) --------------------
__global__ __launch_bounds__(256) void ffn_mfma(const float* __restrict__ t,
    const float* __restrict__ coef1, const _Float16* __restrict__ W1h,
    const float* __restrict__ b1, const _Float16* __restrict__ W2h,
    const float* __restrict__ b2, float* __restrict__ z,
    float* __restrict__ stats2, int N) {
  __shared__ _Float16 hs[64 * HP];  // 17.4 KB
  __shared__ _Float16 us[64 * UP];  // 33.8 KB
  int tid = threadIdx.x;
  int base = blockIdx.x * 64;
  int lane = tid & 63, w = tid >> 6;
  int l15 = lane & 15, quad = lane >> 4;

  for (int i = tid; i < 64 * 32; i += 256) {
    int m = i >> 5, c4 = i & 31;
    float4 tv = ((const float4*)t)[(size_t)(base + m) * 32 + c4];
    float4 ca = ((const float4*)coef1)[c4];
    float4 cc = ((const float4*)coef1)[32 + c4];
    half4 hv;
    hv.x = (_Float16)(tv.x * ca.x + cc.x);
    hv.y = (_Float16)(tv.y * ca.y + cc.y);
    hv.z = (_Float16)(tv.z * ca.z + cc.z);
    hv.w = (_Float16)(tv.w * ca.w + cc.w);
    *(half4*)&hs[m * HP + c4 * 4] = hv;
  }
  __syncthreads();

  int n0 = w * 64;
  half8 afr[4][4];
#pragma unroll
  for (int mt = 0; mt < 4; mt++)
#pragma unroll
    for (int ks = 0; ks < 4; ks++)
      afr[mt][ks] = *(const half8*)&hs[(mt * 16 + l15) * HP + ks * 32 + quad * 8];

#pragma unroll
  for (int nt = 0; nt < 4; nt++) {
    int n = n0 + nt * 16 + l15;
    half8 bfr[4];
#pragma unroll
    for (int ks = 0; ks < 4; ks++)
      bfr[ks] = *(const half8*)&W1h[(size_t)n * 128 + ks * 32 + quad * 8];
    f32x4 acc[4];
#pragma unroll
    for (int mt = 0; mt < 4; mt++) acc[mt] = (f32x4){0.f, 0.f, 0.f, 0.f};
#pragma unroll
    for (int ks = 0; ks < 4; ks++)
#pragma unroll
      for (int mt = 0; mt < 4; mt++)
        acc[mt] = __builtin_amdgcn_mfma_f32_16x16x32_f16(afr[mt][ks], bfr[ks],
                                                          acc[mt], 0, 0, 0);
    float bias = b1[n];
#pragma unroll
    for (int mt = 0; mt < 4; mt++)
#pragma unroll
      for (int r = 0; r < 4; r++)
        us[(mt * 16 + quad * 4 + r) * UP + n] =
            (_Float16)fmaxf(acc[mt][r] + bias, 0.f);
  }
  __syncthreads();

  int n2 = w * 32;
  f32x4 acc2[4][2];
#pragma unroll
  for (int mt = 0; mt < 4; mt++)
#pragma unroll
    for (int nt = 0; nt < 2; nt++) acc2[mt][nt] = (f32x4){0.f, 0.f, 0.f, 0.f};
  for (int ks = 0; ks < 8; ks++) {
    half8 a[4], b[2];
#pragma unroll
    for (int mt = 0; mt < 4; mt++)
      a[mt] = *(const half8*)&us[(mt * 16 + l15) * UP + ks * 32 + quad * 8];
#pragma unroll
    for (int nt = 0; nt < 2; nt++)
      b[nt] = *(const half8*)&W2h[(size_t)(n2 + nt * 16 + l15) * 256 + ks * 32 +
                                  quad * 8];
#pragma unroll
    for (int mt = 0; mt < 4; mt++)
#pragma unroll
      for (int nt = 0; nt < 2; nt++)
        acc2[mt][nt] =
            __builtin_amdgcn_mfma_f32_16x16x32_f16(a[mt], b[nt], acc2[mt][nt], 0, 0, 0);
  }

#pragma unroll
  for (int nt = 0; nt < 2; nt++) {
    int f = n2 + nt * 16 + l15;
    float bz = b2[f];
    float s = 0.f, q = 0.f;
#pragma unroll
    for (int mt = 0; mt < 4; mt++) {
#pragma unroll
      for (int r = 0; r < 4; r++) {
        int row = mt * 16 + quad * 4 + r;
        float hv = (float)hs[row * HP + f];
        float zv = hv + acc2[mt][nt][r] + bz;
        z[(size_t)(base + row) * DIM + f] = zv;
        s += zv;
        q += zv * zv;
      }
    }
    s += __shfl_xor(s, 16);
    s += __shfl_xor(s, 32);
    q += __shfl_xor(q, 16);
    q += __shfl_xor(q, 32);
    if (quad == 0) {
      atomicAdd(&stats2[f], s);
      atomicAdd(&stats2[128 + f], q);
    }
  }
}

// ---------------- final BN2 apply ----------------
__global__ __launch_bounds__(256) void final_apply(const float* __restrict__ z,
    const float* __restrict__ coef2, float* __restrict__ out, int total4) {
  int i = blockIdx.x * 256 + threadIdx.x;
  if (i >= total4) return;
  int f = (i * 4) & 127;
  float4 zv = ((const float4*)z)[i];
  float4 o;
  o.x = zv.x * coef2[f] + coef2[128 + f];
  o.y = zv.y * coef2[f + 1] + coef2[128 + f + 1];
  o.z = zv.z * coef2[f + 2] + coef2[128 + f + 2];
  o.w = zv.w * coef2[f + 3] + coef2[128 + f + 3];
  ((float4*)out)[i] = o;
}

extern "C" void kernel_launch(void* const* d_in, const int* in_sizes, int n_in,
                              void* d_out, int out_size, void* d_ws, size_t ws_size,
                              hipStream_t stream) {
  const float* x = (const float*)d_in[0];
  const int* ei = (const int*)d_in[1];
  const float* Wk = (const float*)d_in[2];
  const float* bk = (const float*)d_in[3];
  const float* Wv = (const float*)d_in[4];
  const float* bv = (const float*)d_in[5];
  const float* Wo = (const float*)d_in[6];
  const float* bo = (const float*)d_in[7];
  const float* bn1_g = (const float*)d_in[8];
  const float* bn1_b = (const float*)d_in[9];
  const float* W1 = (const float*)d_in[10];
  const float* b1 = (const float*)d_in[11];
  const float* W2 = (const float*)d_in[12];
  const float* b2 = (const float*)d_in[13];
  const float* bn2_g = (const float*)d_in[14];
  const float* bn2_b = (const float*)d_in[15];
  float* out = (float*)d_out;

  int N = in_sizes[0] / DIM;   // 40000 (= 625 * 64)
  int E = in_sizes[1] / 2;     // 640000

  // workspace layout:
  // [K16|V16: 20.5 MB fp16] -> reused as tbuf (f32)
  // [attn: 20.5 MB f32]     -> reused as zbuf
  // [W1h|W2h|Wkh|Wvh|Woh fp16] [stats] [coef] [ints]
  _Float16* K16 = (_Float16*)d_ws;
  _Float16* V16 = K16 + (size_t)N * DIM;
  float* attn = (float*)(V16 + (size_t)N * DIM);
  float* tbuf = (float*)d_ws;               // reuses K16/V16 (dead after attn_agg)
  float* zbuf = attn;                       // reuses attn (dead after o_proj)
  _Float16* W1h = (_Float16*)(attn + (size_t)N * DIM);
  _Float16* W2h = W1h + 32768;
  _Float16* Wkh = W2h + 32768;
  _Float16* Wvh = Wkh + 16384;
  _Float16* Woh = Wvh + 16384;
  float* stats = (float*)(Woh + 16384);     // 512 floats: stats1 | stats2
  float* coef = stats + 512;                // 512 floats
  int* cnt = (int*)(coef + 512);
  int* rs = cnt + N;
  int* cursor = rs + N + 1;
  int* esrc = cursor + N;
  int* bsum = esrc + E;

  int nblk = (N + 255) / 256;

  hipMemsetAsync(cnt, 0, (size_t)N * sizeof(int), stream);
  hipMemsetAsync(stats, 0, 512 * sizeof(float), stream);

  conv_wall<<<448, 256, 0, stream>>>(Wk, Wv, Wo, W1, W2, Wkh, Wvh, Woh, W1h, W2h);
  kv_mfma<<<N / 64, 256, 0, stream>>>(x, Wkh, bk, Wvh, bv, K16, V16, N);
  hist_kernel<<<(E + 255) / 256, 256, 0, stream>>>(ei, cnt, E);
  scanA<<<nblk, 256, 0, stream>>>(cnt, rs, bsum, N);
  scanB<<<1, 256, 0, stream>>>(bsum, nblk);
  scanC<<<nblk, 256, 0, stream>>>(rs, bsum, cursor, N, E);
  scatter_kernel<<<(E + 255) / 256, 256, 0, stream>>>(ei, cursor, esrc, E);
  attn_agg<<<(N + 3) / 4, 256, 0, stream>>>(K16, V16, x, rs, esrc, attn, N);
  o_proj_mfma<<<N / 64, 256, 0, stream>>>(attn, x, Woh, bo, tbuf, stats, N);
  bn_fin<<<1, 128, 0, stream>>>(stats, bn1_g, bn1_b, coef, 1.0f / N);
  ffn_mfma<<<N / 64, 256, 0, stream>>>(tbuf, coef, W1h, b1, W2h, b2, zbuf,
                                       stats + 256, N);
  bn_fin<<<1, 128, 0, stream>>>(stats + 256, bn2_g, bn2_b, coef + 256, 1.0f / N);
  final_apply<<<((N * DIM / 4) + 255) / 256, 256, 0, stream>>>(zbuf, coef + 256, out,
                                                               N * DIM / 4);
}

// Round 7
// 305.210 us; speedup vs baseline: 2.7781x; 1.0072x over previous
//
#include <hip/hip_runtime.h>

#define DIM 128

typedef __attribute__((ext_vector_type(4))) _Float16 half4;
typedef __attribute__((ext_vector_type(8))) _Float16 half8;
typedef __attribute__((ext_vector_type(4))) float f32x4;

#define HP 136  // fp16 tile row stride (halfs): 128 + 8 pad (2-way = free)
#define UP 264  // fp16 tile row stride (halfs): 256 + 8 pad

// ---------------- fp32 -> fp16 conversion of all weights ----------------
__global__ __launch_bounds__(256) void conv_wall(const float* __restrict__ Wk,
    const float* __restrict__ Wv, const float* __restrict__ Wo,
    const float* __restrict__ W1, const float* __restrict__ W2,
    _Float16* __restrict__ Wkh, _Float16* __restrict__ Wvh,
    _Float16* __restrict__ Woh, _Float16* __restrict__ W1h,
    _Float16* __restrict__ W2h) {
  int i = blockIdx.x * 256 + threadIdx.x;  // 114688 total
  if (i < 16384) Wkh[i] = (_Float16)Wk[i];
  else if (i < 32768) Wvh[i - 16384] = (_Float16)Wv[i - 16384];
  else if (i < 49152) Woh[i - 32768] = (_Float16)Wo[i - 32768];
  else if (i < 81920) W1h[i - 49152] = (_Float16)W1[i - 49152];
  else W2h[i - 81920] = (_Float16)W2[i - 81920];
}

// ---------------- KV projection via MFMA, interleaved KV output --------------
// KV row layout (256 halfs/node): chunk g = [K[4g..4g+3] | V[4g..4g+3]] (8 halfs).
// Waves 0-1 -> K (Wk), waves 2-3 -> V (Wv); wave owns 64 feats.
__global__ __launch_bounds__(256) void kv_mfma(const float* __restrict__ x,
    const _Float16* __restrict__ Wkh, const float* __restrict__ bk,
    const _Float16* __restrict__ Wvh, const float* __restrict__ bv,
    _Float16* __restrict__ KV, int N) {
  __shared__ _Float16 xs[64 * HP];  // 17.4 KB
  int tid = threadIdx.x;
  int base = blockIdx.x * 64;
  int lane = tid & 63, w = tid >> 6;
  int l15 = lane & 15, quad = lane >> 4;

  for (int i = tid; i < 64 * 32; i += 256) {
    int m = i >> 5, c4 = i & 31;
    float4 tv = ((const float4*)x)[(size_t)(base + m) * 32 + c4];
    half4 hv;
    hv.x = (_Float16)tv.x; hv.y = (_Float16)tv.y;
    hv.z = (_Float16)tv.z; hv.w = (_Float16)tv.w;
    *(half4*)&xs[m * HP + c4 * 4] = hv;
  }
  __syncthreads();

  half8 afr[4][4];
#pragma unroll
  for (int mt = 0; mt < 4; mt++)
#pragma unroll
    for (int ks = 0; ks < 4; ks++)
      afr[mt][ks] = *(const half8*)&xs[(mt * 16 + l15) * HP + ks * 32 + quad * 8];

  const _Float16* W = (w < 2) ? Wkh : Wvh;
  const float* bias = (w < 2) ? bk : bv;
  int voff = (w < 2) ? 0 : 4;
  int c0 = (w & 1) * 64;

#pragma unroll
  for (int nt = 0; nt < 4; nt++) {
    int f = c0 + nt * 16 + l15;
    half8 bfr[4];
#pragma unroll
    for (int ks = 0; ks < 4; ks++)
      bfr[ks] = *(const half8*)&W[(size_t)f * 128 + ks * 32 + quad * 8];
    f32x4 acc[4];
#pragma unroll
    for (int mt = 0; mt < 4; mt++) acc[mt] = (f32x4){0.f, 0.f, 0.f, 0.f};
#pragma unroll
    for (int ks = 0; ks < 4; ks++)
#pragma unroll
      for (int mt = 0; mt < 4; mt++)
        acc[mt] = __builtin_amdgcn_mfma_f32_16x16x32_f16(afr[mt][ks], bfr[ks],
                                                          acc[mt], 0, 0, 0);
    float bb = bias[f];
    int fo = (f >> 2) * 8 + (f & 3) + voff;  // interleaved offset
#pragma unroll
    for (int mt = 0; mt < 4; mt++)
#pragma unroll
      for (int r = 0; r < 4; r++)
        KV[(size_t)(base + mt * 16 + quad * 4 + r) * 256 + fo] =
            (_Float16)(acc[mt][r] + bb);
  }
}

// ---------------- CSR build ----------------
__global__ __launch_bounds__(256) void hist_kernel(const int* __restrict__ ei,
                                                   int* __restrict__ cnt, int E) {
  int e = blockIdx.x * 256 + threadIdx.x;
  if (e < E) atomicAdd(&cnt[ei[E + e]], 1);
}

__global__ __launch_bounds__(256) void scanA(const int* __restrict__ cnt,
    int* __restrict__ rs, int* __restrict__ bsum, int N) {
  __shared__ int s[256];
  int t = threadIdx.x;
  int i = blockIdx.x * 256 + t;
  int v = (i < N) ? cnt[i] : 0;
  s[t] = v;
  __syncthreads();
  for (int off = 1; off < 256; off <<= 1) {
    int add = (t >= off) ? s[t - off] : 0;
    __syncthreads();
    s[t] += add;
    __syncthreads();
  }
  if (i < N) rs[i] = s[t] - v;
  if (t == 255) bsum[blockIdx.x] = s[t];
}

__global__ __launch_bounds__(256) void scanB(int* __restrict__ bsum, int nb) {
  __shared__ int s[256];
  int t = threadIdx.x;
  int v = (t < nb) ? bsum[t] : 0;
  s[t] = v;
  __syncthreads();
  for (int off = 1; off < 256; off <<= 1) {
    int add = (t >= off) ? s[t - off] : 0;
    __syncthreads();
    s[t] += add;
    __syncthreads();
  }
  if (t < nb) bsum[t] = s[t] - v;
}

__global__ __launch_bounds__(256) void scanC(int* __restrict__ rs,
    const int* __restrict__ bsum, int* __restrict__ cursor, int N, int E) {
  int i = blockIdx.x * 256 + threadIdx.x;
  if (i < N) {
    int v = rs[i] + bsum[blockIdx.x];
    rs[i] = v;
    cursor[i] = v;
  }
  if (i == 0) rs[N] = E;
}

__global__ __launch_bounds__(256) void scatter_kernel(const int* __restrict__ ei,
    int* __restrict__ cursor, int* __restrict__ esrc, int E) {
  int e = blockIdx.x * 256 + threadIdx.x;
  if (e < E) {
    int d = ei[E + e];
    int pos = atomicAdd(&cursor[d], 1);
    esrc[pos] = ei[e];
  }
}

// ---------------- fused attention aggregate: one wave per dst node ----------
// Interleaved KV: one dwordx4/lane per edge fetches K half4 + V half4.
// Two 32-lane groups x 2-deep unroll = 4 edges in flight per wave.
__global__ __launch_bounds__(256) void attn_agg(const _Float16* __restrict__ KV,
    const float* __restrict__ x, const int* __restrict__ rs,
    const int* __restrict__ esrc, _Float16* __restrict__ attn16, int N) {
  int wave = threadIdx.x >> 6, lane = threadIdx.x & 63;
  int n = blockIdx.x * 4 + wave;
  if (n >= N) return;
  int l = lane & 31, s = lane >> 5;
  float4 q = *(const float4*)&x[(size_t)n * DIM + 4 * l];
  int beg = rs[n], end = rs[n + 1];
  float a0 = 0.f, a1 = 0.f, a2 = 0.f, a3 = 0.f, dloc = 0.f;
  for (int e = beg + s; e < end; e += 4) {
    int e1 = e + 2;
    bool h1 = e1 < end;
    int src0 = esrc[e];
    int src1 = h1 ? esrc[e1] : src0;
    half8 kv0 = *(const half8*)&KV[(size_t)src0 * 256 + 8 * l];
    half8 kv1 = *(const half8*)&KV[(size_t)src1 * 256 + 8 * l];
    float p0 = (float)kv0[0] * q.x + (float)kv0[1] * q.y +
               (float)kv0[2] * q.z + (float)kv0[3] * q.w;
    float p1 = (float)kv1[0] * q.x + (float)kv1[1] * q.y +
               (float)kv1[2] * q.z + (float)kv1[3] * q.w;
    p0 += __shfl_xor(p0, 1);
    p1 += __shfl_xor(p1, 1);
    p0 += __shfl_xor(p0, 2);
    p1 += __shfl_xor(p1, 2);
    float ev0 = __expf(p0 * 0.25f);
    float ev1 = h1 ? __expf(p1 * 0.25f) : 0.f;
    dloc += ev0 + ev1;
    a0 += ev0 * (float)kv0[4] + ev1 * (float)kv1[4];
    a1 += ev0 * (float)kv0[5] + ev1 * (float)kv1[5];
    a2 += ev0 * (float)kv0[6] + ev1 * (float)kv1[6];
    a3 += ev0 * (float)kv0[7] + ev1 * (float)kv1[7];
  }
  dloc += __shfl_xor(dloc, 32);
  a0 += __shfl_xor(a0, 32);
  a1 += __shfl_xor(a1, 32);
  a2 += __shfl_xor(a2, 32);
  a3 += __shfl_xor(a3, 32);
  if (s == 0) {
    float inv = 1.0f / (dloc + 1e-16f);
    half4 o;
    o.x = (_Float16)(a0 * inv);
    o.y = (_Float16)(a1 * inv);
    o.z = (_Float16)(a2 * inv);
    o.w = (_Float16)(a3 * inv);
    *(half4*)&attn16[(size_t)n * DIM + 4 * l] = o;
  }
}

// ---------------- O-projection via MFMA + residual + BN1 stats ---------------
__global__ __launch_bounds__(256) void o_proj_mfma(const _Float16* __restrict__ attn16,
    const float* __restrict__ x, const _Float16* __restrict__ Woh,
    const float* __restrict__ bo, float* __restrict__ t,
    float* __restrict__ stats, int N) {
  __shared__ _Float16 as16[64 * HP];  // 17.4 KB
  int tid = threadIdx.x;
  int base = blockIdx.x * 64;
  int lane = tid & 63, w = tid >> 6;
  int l15 = lane & 15, quad = lane >> 4;

  for (int i = tid; i < 64 * 16; i += 256) {
    int m = i >> 4, c8 = i & 15;
    *(half8*)&as16[m * HP + c8 * 8] =
        ((const half8*)attn16)[(size_t)(base + m) * 16 + c8];
  }
  __syncthreads();

  half8 afr[4][4];
#pragma unroll
  for (int mt = 0; mt < 4; mt++)
#pragma unroll
    for (int ks = 0; ks < 4; ks++)
      afr[mt][ks] = *(const half8*)&as16[(mt * 16 + l15) * HP + ks * 32 + quad * 8];

  int c0 = w * 32;
  f32x4 acc[4][2];
#pragma unroll
  for (int mt = 0; mt < 4; mt++)
#pragma unroll
    for (int nt = 0; nt < 2; nt++) acc[mt][nt] = (f32x4){0.f, 0.f, 0.f, 0.f};
#pragma unroll
  for (int ks = 0; ks < 4; ks++) {
    half8 b[2];
#pragma unroll
    for (int nt = 0; nt < 2; nt++)
      b[nt] = *(const half8*)&Woh[(size_t)(c0 + nt * 16 + l15) * 128 + ks * 32 +
                                  quad * 8];
#pragma unroll
    for (int mt = 0; mt < 4; mt++)
#pragma unroll
      for (int nt = 0; nt < 2; nt++)
        acc[mt][nt] =
            __builtin_amdgcn_mfma_f32_16x16x32_f16(afr[mt][ks], b[nt], acc[mt][nt], 0, 0, 0);
  }

#pragma unroll
  for (int nt = 0; nt < 2; nt++) {
    int f = c0 + nt * 16 + l15;
    float bb = bo[f];
    float s = 0.f, q = 0.f;
#pragma unroll
    for (int mt = 0; mt < 4; mt++) {
#pragma unroll
      for (int r = 0; r < 4; r++) {
        int row = mt * 16 + quad * 4 + r;
        float tv = acc[mt][nt][r] + bb + x[(size_t)(base + row) * DIM + f];
        t[(size_t)(base + row) * DIM + f] = tv;
        s += tv;
        q += tv * tv;
      }
    }
    s += __shfl_xor(s, 16);
    s += __shfl_xor(s, 32);
    q += __shfl_xor(q, 16);
    q += __shfl_xor(q, 32);
    if (quad == 0) {
      atomicAdd(&stats[f], s);
      atomicAdd(&stats[128 + f], q);
    }
  }
}

// ---------------- BN finalize ----------------
__global__ void bn_fin(const float* __restrict__ stats, const float* __restrict__ g,
                       const float* __restrict__ b, float* __restrict__ coef,
                       float invN) {
  int f = threadIdx.x;
  float mu = stats[f] * invN;
  float var = stats[128 + f] * invN - mu * mu;
  float a = rsqrtf(var + 1e-5f) * g[f];
  coef[f] = a;
  coef[128 + f] = b[f] - mu * a;
}

// ---------------- fused FFN via MFMA (fp16 in, fp32 acc) --------------------
__global__ __launch_bounds__(256) void ffn_mfma(const float* __restrict__ t,
    const float* __restrict__ coef1, const _Float16* __restrict__ W1h,
    const float* __restrict__ b1, const _Float16* __restrict__ W2h,
    const float* __restrict__ b2, float* __restrict__ z,
    float* __restrict__ stats2, int N) {
  __shared__ _Float16 hs[64 * HP];  // 17.4 KB
  __shared__ _Float16 us[64 * UP];  // 33.8 KB
  int tid = threadIdx.x;
  int base = blockIdx.x * 64;
  int lane = tid & 63, w = tid >> 6;
  int l15 = lane & 15, quad = lane >> 4;

  for (int i = tid; i < 64 * 32; i += 256) {
    int m = i >> 5, c4 = i & 31;
    float4 tv = ((const float4*)t)[(size_t)(base + m) * 32 + c4];
    float4 ca = ((const float4*)coef1)[c4];
    float4 cc = ((const float4*)coef1)[32 + c4];
    half4 hv;
    hv.x = (_Float16)(tv.x * ca.x + cc.x);
    hv.y = (_Float16)(tv.y * ca.y + cc.y);
    hv.z = (_Float16)(tv.z * ca.z + cc.z);
    hv.w = (_Float16)(tv.w * ca.w + cc.w);
    *(half4*)&hs[m * HP + c4 * 4] = hv;
  }
  __syncthreads();

  int n0 = w * 64;
  half8 afr[4][4];
#pragma unroll
  for (int mt = 0; mt < 4; mt++)
#pragma unroll
    for (int ks = 0; ks < 4; ks++)
      afr[mt][ks] = *(const half8*)&hs[(mt * 16 + l15) * HP + ks * 32 + quad * 8];

#pragma unroll
  for (int nt = 0; nt < 4; nt++) {
    int n = n0 + nt * 16 + l15;
    half8 bfr[4];
#pragma unroll
    for (int ks = 0; ks < 4; ks++)
      bfr[ks] = *(const half8*)&W1h[(size_t)n * 128 + ks * 32 + quad * 8];
    f32x4 acc[4];
#pragma unroll
    for (int mt = 0; mt < 4; mt++) acc[mt] = (f32x4){0.f, 0.f, 0.f, 0.f};
#pragma unroll
    for (int ks = 0; ks < 4; ks++)
#pragma unroll
      for (int mt = 0; mt < 4; mt++)
        acc[mt] = __builtin_amdgcn_mfma_f32_16x16x32_f16(afr[mt][ks], bfr[ks],
                                                          acc[mt], 0, 0, 0);
    float bias = b1[n];
#pragma unroll
    for (int mt = 0; mt < 4; mt++)
#pragma unroll
      for (int r = 0; r < 4; r++)
        us[(mt * 16 + quad * 4 + r) * UP + n] =
            (_Float16)fmaxf(acc[mt][r] + bias, 0.f);
  }
  __syncthreads();

  int n2 = w * 32;
  f32x4 acc2[4][2];
#pragma unroll
  for (int mt = 0; mt < 4; mt++)
#pragma unroll
    for (int nt = 0; nt < 2; nt++) acc2[mt][nt] = (f32x4){0.f, 0.f, 0.f, 0.f};
  for (int ks = 0; ks < 8; ks++) {
    half8 a[4], b[2];
#pragma unroll
    for (int mt = 0; mt < 4; mt++)
      a[mt] = *(const half8*)&us[(mt * 16 + l15) * UP + ks * 32 + quad * 8];
#pragma unroll
    for (int nt = 0; nt < 2; nt++)
      b[nt] = *(const half8*)&W2h[(size_t)(n2 + nt * 16 + l15) * 256 + ks * 32 +
                                  quad * 8];
#pragma unroll
    for (int mt = 0; mt < 4; mt++)
#pragma unroll
      for (int nt = 0; nt < 2; nt++)
        acc2[mt][nt] =
            __builtin_amdgcn_mfma_f32_16x16x32_f16(a[mt], b[nt], acc2[mt][nt], 0, 0, 0);
  }

#pragma unroll
  for (int nt = 0; nt < 2; nt++) {
    int f = n2 + nt * 16 + l15;
    float bz = b2[f];
    float s = 0.f, q = 0.f;
#pragma unroll
    for (int mt = 0; mt < 4; mt++) {
#pragma unroll
      for (int r = 0; r < 4; r++) {
        int row = mt * 16 + quad * 4 + r;
        float hv = (float)hs[row * HP + f];
        float zv = hv + acc2[mt][nt][r] + bz;
        z[(size_t)(base + row) * DIM + f] = zv;
        s += zv;
        q += zv * zv;
      }
    }
    s += __shfl_xor(s, 16);
    s += __shfl_xor(s, 32);
    q += __shfl_xor(q, 16);
    q += __shfl_xor(q, 32);
    if (quad == 0) {
      atomicAdd(&stats2[f], s);
      atomicAdd(&stats2[128 + f], q);
    }
  }
}

// ---------------- final BN2 apply ----------------
__global__ __launch_bounds__(256) void final_apply(const float* __restrict__ z,
    const float* __restrict__ coef2, float* __restrict__ out, int total4) {
  int i = blockIdx.x * 256 + threadIdx.x;
  if (i >= total4) return;
  int f = (i * 4) & 127;
  float4 zv = ((const float4*)z)[i];
  float4 o;
  o.x = zv.x * coef2[f] + coef2[128 + f];
  o.y = zv.y * coef2[f + 1] + coef2[128 + f + 1];
  o.z = zv.z * coef2[f + 2] + coef2[128 + f + 2];
  o.w = zv.w * coef2[f + 3] + coef2[128 + f + 3];
  ((float4*)out)[i] = o;
}

extern "C" void kernel_launch(void* const* d_in, const int* in_sizes, int n_in,
                              void* d_out, int out_size, void* d_ws, size_t ws_size,
                              hipStream_t stream) {
  const float* x = (const float*)d_in[0];
  const int* ei = (const int*)d_in[1];
  const float* Wk = (const float*)d_in[2];
  const float* bk = (const float*)d_in[3];
  const float* Wv = (const float*)d_in[4];
  const float* bv = (const float*)d_in[5];
  const float* Wo = (const float*)d_in[6];
  const float* bo = (const float*)d_in[7];
  const float* bn1_g = (const float*)d_in[8];
  const float* bn1_b = (const float*)d_in[9];
  const float* W1 = (const float*)d_in[10];
  const float* b1 = (const float*)d_in[11];
  const float* W2 = (const float*)d_in[12];
  const float* b2 = (const float*)d_in[13];
  const float* bn2_g = (const float*)d_in[14];
  const float* bn2_b = (const float*)d_in[15];
  float* out = (float*)d_out;

  int N = in_sizes[0] / DIM;   // 40000 (= 625 * 64)
  int E = in_sizes[1] / 2;     // 640000

  // workspace layout:
  // [A: KV16 interleaved 20.5 MB] -> reused as tbuf (f32)
  // [B: attn16 10.25 MB fp16]
  // [C: zbuf 20.5 MB f32]
  // [weights fp16] [stats] [coef] [ints]
  _Float16* KV = (_Float16*)d_ws;
  _Float16* attn16 = KV + (size_t)N * 256;
  float* zbuf = (float*)(attn16 + (size_t)N * DIM);
  float* tbuf = (float*)d_ws;               // reuses KV (dead after attn_agg)
  _Float16* W1h = (_Float16*)(zbuf + (size_t)N * DIM);
  _Float16* W2h = W1h + 32768;
  _Float16* Wkh = W2h + 32768;
  _Float16* Wvh = Wkh + 16384;
  _Float16* Woh = Wvh + 16384;
  float* stats = (float*)(Woh + 16384);     // 512 floats: stats1 | stats2
  float* coef = stats + 512;                // 512 floats
  int* cnt = (int*)(coef + 512);
  int* rs = cnt + N;
  int* cursor = rs + N + 1;
  int* esrc = cursor + N;
  int* bsum = esrc + E;

  int nblk = (N + 255) / 256;

  hipMemsetAsync(cnt, 0, (size_t)N * sizeof(int), stream);
  hipMemsetAsync(stats, 0, 512 * sizeof(float), stream);

  conv_wall<<<448, 256, 0, stream>>>(Wk, Wv, Wo, W1, W2, Wkh, Wvh, Woh, W1h, W2h);
  kv_mfma<<<N / 64, 256, 0, stream>>>(x, Wkh, bk, Wvh, bv, KV, N);
  hist_kernel<<<(E + 255) / 256, 256, 0, stream>>>(ei, cnt, E);
  scanA<<<nblk, 256, 0, stream>>>(cnt, rs, bsum, N);
  scanB<<<1, 256, 0, stream>>>(bsum, nblk);
  scanC<<<nblk, 256, 0, stream>>>(rs, bsum, cursor, N, E);
  scatter_kernel<<<(E + 255) / 256, 256, 0, stream>>>(ei, cursor, esrc, E);
  attn_agg<<<(N + 3) / 4, 256, 0, stream>>>(KV, x, rs, esrc, attn16, N);
  o_proj_mfma<<<N / 64, 256, 0, stream>>>(attn16, x, Woh, bo, tbuf, stats, N);
  bn_fin<<<1, 128, 0, stream>>>(stats, bn1_g, bn1_b, coef, 1.0f / N);
  ffn_mfma<<<N / 64, 256, 0, stream>>>(tbuf, coef, W1h, b1, W2h, b2, zbuf,
                                       stats + 256, N);
  bn_fin<<<1, 128, 0, stream>>>(stats + 256, bn2_g, bn2_b, coef + 256, 1.0f / N);
  final_apply<<<((N * DIM / 4) + 255) / 256, 256, 0, stream>>>(zbuf, coef + 256, out,
                                                               N * DIM / 4);
}

// Round 8
// 260.381 us; speedup vs baseline: 3.2564x; 1.1722x over previous
//
#include <hip/hip_runtime.h>

#define DIM 128

typedef __attribute__((ext_vector_type(4))) _Float16 half4;
typedef __attribute__((ext_vector_type(8))) _Float16 half8;
typedef __attribute__((ext_vector_type(4))) float f32x4;

#define HP 136  // fp16 tile row stride (halfs): 128 + 8 pad (2-way = free)
#define UP 264  // fp16 tile row stride (halfs): 256 + 8 pad

// ------- fp32 -> fp16 conversion of all weights + zero cnt/stats -------------
__global__ __launch_bounds__(256) void conv_wall(const float* __restrict__ Wk,
    const float* __restrict__ Wv, const float* __restrict__ Wo,
    const float* __restrict__ W1, const float* __restrict__ W2,
    _Float16* __restrict__ Wkh, _Float16* __restrict__ Wvh,
    _Float16* __restrict__ Woh, _Float16* __restrict__ W1h,
    _Float16* __restrict__ W2h, int* __restrict__ cnt, float* __restrict__ stats,
    int N) {
  int i = blockIdx.x * 256 + threadIdx.x;  // 114688 total
  if (i < 16384) Wkh[i] = (_Float16)Wk[i];
  else if (i < 32768) Wvh[i - 16384] = (_Float16)Wv[i - 16384];
  else if (i < 49152) Woh[i - 32768] = (_Float16)Wo[i - 32768];
  else if (i < 81920) W1h[i - 49152] = (_Float16)W1[i - 49152];
  else W2h[i - 81920] = (_Float16)W2[i - 81920];
  if (i < N) cnt[i] = 0;
  if (i < 512) stats[i] = 0.f;
}

// ---------------- KV projection via MFMA, interleaved KV output --------------
__global__ __launch_bounds__(256) void kv_mfma(const float* __restrict__ x,
    const _Float16* __restrict__ Wkh, const float* __restrict__ bk,
    const _Float16* __restrict__ Wvh, const float* __restrict__ bv,
    _Float16* __restrict__ KV, int N) {
  __shared__ _Float16 xs[64 * HP];  // 17.4 KB
  int tid = threadIdx.x;
  int base = blockIdx.x * 64;
  int lane = tid & 63, w = tid >> 6;
  int l15 = lane & 15, quad = lane >> 4;

  for (int i = tid; i < 64 * 32; i += 256) {
    int m = i >> 5, c4 = i & 31;
    float4 tv = ((const float4*)x)[(size_t)(base + m) * 32 + c4];
    half4 hv;
    hv.x = (_Float16)tv.x; hv.y = (_Float16)tv.y;
    hv.z = (_Float16)tv.z; hv.w = (_Float16)tv.w;
    *(half4*)&xs[m * HP + c4 * 4] = hv;
  }
  __syncthreads();

  half8 afr[4][4];
#pragma unroll
  for (int mt = 0; mt < 4; mt++)
#pragma unroll
    for (int ks = 0; ks < 4; ks++)
      afr[mt][ks] = *(const half8*)&xs[(mt * 16 + l15) * HP + ks * 32 + quad * 8];

  const _Float16* W = (w < 2) ? Wkh : Wvh;
  const float* bias = (w < 2) ? bk : bv;
  int voff = (w < 2) ? 0 : 4;
  int c0 = (w & 1) * 64;

#pragma unroll
  for (int nt = 0; nt < 4; nt++) {
    int f = c0 + nt * 16 + l15;
    half8 bfr[4];
#pragma unroll
    for (int ks = 0; ks < 4; ks++)
      bfr[ks] = *(const half8*)&W[(size_t)f * 128 + ks * 32 + quad * 8];
    f32x4 acc[4];
#pragma unroll
    for (int mt = 0; mt < 4; mt++) acc[mt] = (f32x4){0.f, 0.f, 0.f, 0.f};
#pragma unroll
    for (int ks = 0; ks < 4; ks++)
#pragma unroll
      for (int mt = 0; mt < 4; mt++)
        acc[mt] = __builtin_amdgcn_mfma_f32_16x16x32_f16(afr[mt][ks], bfr[ks],
                                                          acc[mt], 0, 0, 0);
    float bb = bias[f];
    int fo = (f >> 2) * 8 + (f & 3) + voff;  // interleaved offset
#pragma unroll
    for (int mt = 0; mt < 4; mt++)
#pragma unroll
      for (int r = 0; r < 4; r++)
        KV[(size_t)(base + mt * 16 + quad * 4 + r) * 256 + fo] =
            (_Float16)(acc[mt][r] + bb);
  }
}

// ---------------- CSR build: hist with rank capture ----------------
__global__ __launch_bounds__(256) void hist_rank(const int* __restrict__ ei,
    int* __restrict__ cnt, int* __restrict__ rank, int E) {
  int e = blockIdx.x * 256 + threadIdx.x;
  if (e < E) rank[e] = atomicAdd(&cnt[ei[E + e]], 1);
}

__global__ __launch_bounds__(256) void scanA(const int* __restrict__ cnt,
    int* __restrict__ rs, int* __restrict__ bsum, int N) {
  __shared__ int s[256];
  int t = threadIdx.x;
  int i = blockIdx.x * 256 + t;
  int v = (i < N) ? cnt[i] : 0;
  s[t] = v;
  __syncthreads();
  for (int off = 1; off < 256; off <<= 1) {
    int add = (t >= off) ? s[t - off] : 0;
    __syncthreads();
    s[t] += add;
    __syncthreads();
  }
  if (i < N) rs[i] = s[t] - v;
  if (t == 255) bsum[blockIdx.x] = s[t];
}

__global__ __launch_bounds__(256) void scanB(int* __restrict__ bsum, int nb) {
  __shared__ int s[256];
  int t = threadIdx.x;
  int v = (t < nb) ? bsum[t] : 0;
  s[t] = v;
  __syncthreads();
  for (int off = 1; off < 256; off <<= 1) {
    int add = (t >= off) ? s[t - off] : 0;
    __syncthreads();
    s[t] += add;
    __syncthreads();
  }
  if (t < nb) bsum[t] = s[t] - v;
}

__global__ __launch_bounds__(256) void scanC(int* __restrict__ rs,
    const int* __restrict__ bsum, int N, int E) {
  int i = blockIdx.x * 256 + threadIdx.x;
  if (i < N) rs[i] += bsum[blockIdx.x];
  if (i == 0) rs[N] = E;
}

// ---------------- atomic-free scatter ----------------
__global__ __launch_bounds__(256) void scatter2(const int* __restrict__ ei,
    const int* __restrict__ rs, const int* __restrict__ rank,
    int* __restrict__ esrc, int E) {
  int e = blockIdx.x * 256 + threadIdx.x;
  if (e < E) esrc[rs[ei[E + e]] + rank[e]] = ei[e];
}

// ---------------- fused attention aggregate: one wave per dst node ----------
// Interleaved KV; two 32-lane groups x 4-deep unroll = 8 edges in flight/wave.
__global__ __launch_bounds__(256) void attn_agg(const _Float16* __restrict__ KV,
    const float* __restrict__ x, const int* __restrict__ rs,
    const int* __restrict__ esrc, _Float16* __restrict__ attn16, int N) {
  int wave = threadIdx.x >> 6, lane = threadIdx.x & 63;
  int n = blockIdx.x * 4 + wave;
  if (n >= N) return;
  int l = lane & 31, s = lane >> 5;
  float4 q = *(const float4*)&x[(size_t)n * DIM + 4 * l];
  int beg = rs[n], end = rs[n + 1];
  float a0 = 0.f, a1 = 0.f, a2 = 0.f, a3 = 0.f, dloc = 0.f;
  for (int e = beg + s; e < end; e += 8) {
    bool hh[4];
    int ss[4];
#pragma unroll
    for (int u = 0; u < 4; u++) hh[u] = (e + 2 * u) < end;
    ss[0] = esrc[e];
#pragma unroll
    for (int u = 1; u < 4; u++) ss[u] = hh[u] ? esrc[e + 2 * u] : ss[0];
    half8 kv[4];
#pragma unroll
    for (int u = 0; u < 4; u++)
      kv[u] = *(const half8*)&KV[(size_t)ss[u] * 256 + 8 * l];
    float p[4];
#pragma unroll
    for (int u = 0; u < 4; u++)
      p[u] = (float)kv[u][0] * q.x + (float)kv[u][1] * q.y +
             (float)kv[u][2] * q.z + (float)kv[u][3] * q.w;
#pragma unroll
    for (int u = 0; u < 4; u++) p[u] += __shfl_xor(p[u], 1);
#pragma unroll
    for (int u = 0; u < 4; u++) p[u] += __shfl_xor(p[u], 2);
    float ev[4];
#pragma unroll
    for (int u = 0; u < 4; u++) ev[u] = hh[u] ? __expf(p[u] * 0.25f) : 0.f;
#pragma unroll
    for (int u = 0; u < 4; u++) {
      dloc += ev[u];
      a0 += ev[u] * (float)kv[u][4];
      a1 += ev[u] * (float)kv[u][5];
      a2 += ev[u] * (float)kv[u][6];
      a3 += ev[u] * (float)kv[u][7];
    }
  }
  dloc += __shfl_xor(dloc, 32);
  a0 += __shfl_xor(a0, 32);
  a1 += __shfl_xor(a1, 32);
  a2 += __shfl_xor(a2, 32);
  a3 += __shfl_xor(a3, 32);
  if (s == 0) {
    float inv = 1.0f / (dloc + 1e-16f);
    half4 o;
    o.x = (_Float16)(a0 * inv);
    o.y = (_Float16)(a1 * inv);
    o.z = (_Float16)(a2 * inv);
    o.w = (_Float16)(a3 * inv);
    *(half4*)&attn16[(size_t)n * DIM + 4 * l] = o;
  }
}

// ---------------- O-projection via MFMA + residual + BN1 stats ---------------
__global__ __launch_bounds__(256) void o_proj_mfma(const _Float16* __restrict__ attn16,
    const float* __restrict__ x, const _Float16* __restrict__ Woh,
    const float* __restrict__ bo, float* __restrict__ t,
    float* __restrict__ stats, int N) {
  __shared__ _Float16 as16[64 * HP];  // 17.4 KB
  int tid = threadIdx.x;
  int base = blockIdx.x * 64;
  int lane = tid & 63, w = tid >> 6;
  int l15 = lane & 15, quad = lane >> 4;

  for (int i = tid; i < 64 * 16; i += 256) {
    int m = i >> 4, c8 = i & 15;
    *(half8*)&as16[m * HP + c8 * 8] =
        ((const half8*)attn16)[(size_t)(base + m) * 16 + c8];
  }
  __syncthreads();

  half8 afr[4][4];
#pragma unroll
  for (int mt = 0; mt < 4; mt++)
#pragma unroll
    for (int ks = 0; ks < 4; ks++)
      afr[mt][ks] = *(const half8*)&as16[(mt * 16 + l15) * HP + ks * 32 + quad * 8];

  int c0 = w * 32;
  f32x4 acc[4][2];
#pragma unroll
  for (int mt = 0; mt < 4; mt++)
#pragma unroll
    for (int nt = 0; nt < 2; nt++) acc[mt][nt] = (f32x4){0.f, 0.f, 0.f, 0.f};
#pragma unroll
  for (int ks = 0; ks < 4; ks++) {
    half8 b[2];
#pragma unroll
    for (int nt = 0; nt < 2; nt++)
      b[nt] = *(const half8*)&Woh[(size_t)(c0 + nt * 16 + l15) * 128 + ks * 32 +
                                  quad * 8];
#pragma unroll
    for (int mt = 0; mt < 4; mt++)
#pragma unroll
      for (int nt = 0; nt < 2; nt++)
        acc[mt][nt] =
            __builtin_amdgcn_mfma_f32_16x16x32_f16(afr[mt][ks], b[nt], acc[mt][nt], 0, 0, 0);
  }

#pragma unroll
  for (int nt = 0; nt < 2; nt++) {
    int f = c0 + nt * 16 + l15;
    float bb = bo[f];
    float s = 0.f, q = 0.f;
#pragma unroll
    for (int mt = 0; mt < 4; mt++) {
#pragma unroll
      for (int r = 0; r < 4; r++) {
        int row = mt * 16 + quad * 4 + r;
        float tv = acc[mt][nt][r] + bb + x[(size_t)(base + row) * DIM + f];
        t[(size_t)(base + row) * DIM + f] = tv;
        s += tv;
        q += tv * tv;
      }
    }
    s += __shfl_xor(s, 16);
    s += __shfl_xor(s, 32);
    q += __shfl_xor(q, 16);
    q += __shfl_xor(q, 32);
    if (quad == 0) {
      atomicAdd(&stats[f], s);
      atomicAdd(&stats[128 + f], q);
    }
  }
}

// ------- fused FFN via MFMA; BN1 coef derived per-block from stats ----------
__global__ __launch_bounds__(256) void ffn_mfma(const float* __restrict__ t,
    const float* __restrict__ stats1, const float* __restrict__ g1,
    const float* __restrict__ bb1, const _Float16* __restrict__ W1h,
    const float* __restrict__ b1, const _Float16* __restrict__ W2h,
    const float* __restrict__ b2, float* __restrict__ z,
    float* __restrict__ stats2, float invN, int N) {
  __shared__ _Float16 hs[64 * HP];  // 17.4 KB
  __shared__ _Float16 us[64 * UP];  // 33.8 KB
  __shared__ float cf[256];
  int tid = threadIdx.x;
  int base = blockIdx.x * 64;
  int lane = tid & 63, w = tid >> 6;
  int l15 = lane & 15, quad = lane >> 4;

  if (tid < 128) {
    float mu = stats1[tid] * invN;
    float var = stats1[128 + tid] * invN - mu * mu;
    float a = rsqrtf(var + 1e-5f) * g1[tid];
    cf[tid] = a;
    cf[128 + tid] = bb1[tid] - mu * a;
  }
  __syncthreads();

  for (int i = tid; i < 64 * 32; i += 256) {
    int m = i >> 5, c4 = i & 31;
    float4 tv = ((const float4*)t)[(size_t)(base + m) * 32 + c4];
    float4 ca = ((const float4*)cf)[c4];
    float4 cc = ((const float4*)cf)[32 + c4];
    half4 hv;
    hv.x = (_Float16)(tv.x * ca.x + cc.x);
    hv.y = (_Float16)(tv.y * ca.y + cc.y);
    hv.z = (_Float16)(tv.z * ca.z + cc.z);
    hv.w = (_Float16)(tv.w * ca.w + cc.w);
    *(half4*)&hs[m * HP + c4 * 4] = hv;
  }
  __syncthreads();

  int n0 = w * 64;
  half8 afr[4][4];
#pragma unroll
  for (int mt = 0; mt < 4; mt++)
#pragma unroll
    for (int ks = 0; ks < 4; ks++)
      afr[mt][ks] = *(const half8*)&hs[(mt * 16 + l15) * HP + ks * 32 + quad * 8];

#pragma unroll
  for (int nt = 0; nt < 4; nt++) {
    int n = n0 + nt * 16 + l15;
    half8 bfr[4];
#pragma unroll
    for (int ks = 0; ks < 4; ks++)
      bfr[ks] = *(const half8*)&W1h[(size_t)n * 128 + ks * 32 + quad * 8];
    f32x4 acc[4];
#pragma unroll
    for (int mt = 0; mt < 4; mt++) acc[mt] = (f32x4){0.f, 0.f, 0.f, 0.f};
#pragma unroll
    for (int ks = 0; ks < 4; ks++)
#pragma unroll
      for (int mt = 0; mt < 4; mt++)
        acc[mt] = __builtin_amdgcn_mfma_f32_16x16x32_f16(afr[mt][ks], bfr[ks],
                                                          acc[mt], 0, 0, 0);
    float bias = b1[n];
#pragma unroll
    for (int mt = 0; mt < 4; mt++)
#pragma unroll
      for (int r = 0; r < 4; r++)
        us[(mt * 16 + quad * 4 + r) * UP + n] =
            (_Float16)fmaxf(acc[mt][r] + bias, 0.f);
  }
  __syncthreads();

  int n2 = w * 32;
  f32x4 acc2[4][2];
#pragma unroll
  for (int mt = 0; mt < 4; mt++)
#pragma unroll
    for (int nt = 0; nt < 2; nt++) acc2[mt][nt] = (f32x4){0.f, 0.f, 0.f, 0.f};
  for (int ks = 0; ks < 8; ks++) {
    half8 a[4], b[2];
#pragma unroll
    for (int mt = 0; mt < 4; mt++)
      a[mt] = *(const half8*)&us[(mt * 16 + l15) * UP + ks * 32 + quad * 8];
#pragma unroll
    for (int nt = 0; nt < 2; nt++)
      b[nt] = *(const half8*)&W2h[(size_t)(n2 + nt * 16 + l15) * 256 + ks * 32 +
                                  quad * 8];
#pragma unroll
    for (int mt = 0; mt < 4; mt++)
#pragma unroll
      for (int nt = 0; nt < 2; nt++)
        acc2[mt][nt] =
            __builtin_amdgcn_mfma_f32_16x16x32_f16(a[mt], b[nt], acc2[mt][nt], 0, 0, 0);
  }

#pragma unroll
  for (int nt = 0; nt < 2; nt++) {
    int f = n2 + nt * 16 + l15;
    float bz = b2[f];
    float s = 0.f, q = 0.f;
#pragma unroll
    for (int mt = 0; mt < 4; mt++) {
#pragma unroll
      for (int r = 0; r < 4; r++) {
        int row = mt * 16 + quad * 4 + r;
        float hv = (float)hs[row * HP + f];
        float zv = hv + acc2[mt][nt][r] + bz;
        z[(size_t)(base + row) * DIM + f] = zv;
        s += zv;
        q += zv * zv;
      }
    }
    s += __shfl_xor(s, 16);
    s += __shfl_xor(s, 32);
    q += __shfl_xor(q, 16);
    q += __shfl_xor(q, 32);
    if (quad == 0) {
      atomicAdd(&stats2[f], s);
      atomicAdd(&stats2[128 + f], q);
    }
  }
}

// -------- final BN2 apply; coef derived per-block from stats2 ----------------
__global__ __launch_bounds__(256) void final_apply(const float* __restrict__ z,
    const float* __restrict__ stats2, const float* __restrict__ g2,
    const float* __restrict__ bb2, float* __restrict__ out, float invN,
    int total4) {
  __shared__ float cf[256];
  int tid = threadIdx.x;
  if (tid < 128) {
    float mu = stats2[tid] * invN;
    float var = stats2[128 + tid] * invN - mu * mu;
    float a = rsqrtf(var + 1e-5f) * g2[tid];
    cf[tid] = a;
    cf[128 + tid] = bb2[tid] - mu * a;
  }
  __syncthreads();
  int i = blockIdx.x * 256 + tid;
  if (i >= total4) return;
  int f = (i * 4) & 127;
  float4 zv = ((const float4*)z)[i];
  float4 o;
  o.x = zv.x * cf[f] + cf[128 + f];
  o.y = zv.y * cf[f + 1] + cf[128 + f + 1];
  o.z = zv.z * cf[f + 2] + cf[128 + f + 2];
  o.w = zv.w * cf[f + 3] + cf[128 + f + 3];
  ((float4*)out)[i] = o;
}

extern "C" void kernel_launch(void* const* d_in, const int* in_sizes, int n_in,
                              void* d_out, int out_size, void* d_ws, size_t ws_size,
                              hipStream_t stream) {
  const float* x = (const float*)d_in[0];
  const int* ei = (const int*)d_in[1];
  const float* Wk = (const float*)d_in[2];
  const float* bk = (const float*)d_in[3];
  const float* Wv = (const float*)d_in[4];
  const float* bv = (const float*)d_in[5];
  const float* Wo = (const float*)d_in[6];
  const float* bo = (const float*)d_in[7];
  const float* bn1_g = (const float*)d_in[8];
  const float* bn1_b = (const float*)d_in[9];
  const float* W1 = (const float*)d_in[10];
  const float* b1 = (const float*)d_in[11];
  const float* W2 = (const float*)d_in[12];
  const float* b2 = (const float*)d_in[13];
  const float* bn2_g = (const float*)d_in[14];
  const float* bn2_b = (const float*)d_in[15];
  float* out = (float*)d_out;

  int N = in_sizes[0] / DIM;   // 40000 (= 625 * 64)
  int E = in_sizes[1] / 2;     // 640000

  _Float16* KV = (_Float16*)d_ws;
  _Float16* attn16 = KV + (size_t)N * 256;
  float* zbuf = (float*)(attn16 + (size_t)N * DIM);
  float* tbuf = (float*)d_ws;               // reuses KV (dead after attn_agg)
  _Float16* W1h = (_Float16*)(zbuf + (size_t)N * DIM);
  _Float16* W2h = W1h + 32768;
  _Float16* Wkh = W2h + 32768;
  _Float16* Wvh = Wkh + 16384;
  _Float16* Woh = Wvh + 16384;
  float* stats = (float*)(Woh + 16384);     // 512 floats: stats1 | stats2
  int* cnt = (int*)(stats + 512);
  int* rs = cnt + N;          // N+1
  int* rank = rs + N + 1;     // E
  int* esrc = rank + E;       // E
  int* bsum = esrc + E;       // up to 256

  int nblk = (N + 255) / 256;
  float invN = 1.0f / N;

  conv_wall<<<448, 256, 0, stream>>>(Wk, Wv, Wo, W1, W2, Wkh, Wvh, Woh, W1h, W2h,
                                     cnt, stats, N);
  kv_mfma<<<N / 64, 256, 0, stream>>>(x, Wkh, bk, Wvh, bv, KV, N);
  hist_rank<<<(E + 255) / 256, 256, 0, stream>>>(ei, cnt, rank, E);
  scanA<<<nblk, 256, 0, stream>>>(cnt, rs, bsum, N);
  scanB<<<1, 256, 0, stream>>>(bsum, nblk);
  scanC<<<nblk, 256, 0, stream>>>(rs, bsum, N, E);
  scatter2<<<(E + 255) / 256, 256, 0, stream>>>(ei, rs, rank, esrc, E);
  attn_agg<<<(N + 3) / 4, 256, 0, stream>>>(KV, x, rs, esrc, attn16, N);
  o_proj_mfma<<<N / 64, 256, 0, stream>>>(attn16, x, Woh, bo, tbuf, stats, N);
  ffn_mfma<<<N / 64, 256, 0, stream>>>(tbuf, stats, bn1_g, bn1_b, W1h, b1, W2h, b2,
                                       zbuf, stats + 256, invN, N);
  final_apply<<<((N * DIM / 4) + 255) / 256, 256, 0, stream>>>(
      zbuf, stats + 256, bn2_g, bn2_b, out, invN, N * DIM / 4);
}